// Round 7
// baseline (452.919 us; speedup 1.0000x reference)
//
#include <hip/hip_runtime.h>
#include <hip/hip_bf16.h>
#include <math.h>

#define B_ 4
#define S_ 1024
#define D_ 1024
#define H_ 16
#define HD_ 64
#define M_ 4096
#define E_ 1024

using bf16 = __hip_bfloat16;
typedef short bf16x8 __attribute__((ext_vector_type(8)));
typedef float f32x4 __attribute__((ext_vector_type(4)));

__device__ __forceinline__ void gl_lds16(const void* g, void* l) {
    __builtin_amdgcn_global_load_lds(
        (__attribute__((address_space(1))) void*)(g),
        (__attribute__((address_space(3))) void*)(l), 16, 0, 0);
}

// LDS swizzle (R9, measured): physical = logical ^ ((row&7)<<4) on
// [rows][64 k-elem] bf16 tiles (row stride 128 B == bank period). Conflicts
// 6.29M -> 0 on the GEMM engines. Source pre-swizzle in 16B-chunk space:
// c ^= (row&7). Fragment-read XOR ((cl&7)<<4) is lane-constant, hoisted.
// R14 applied the same geometry to attn (replacing the +72-pad 8-way layout).

// Engine lessons (R4-R15, measured):
//  - 256x256 8-phase + swizzle + counted vmcnt: 849 TF @ K=1024 == m248
//    reference rate for this shape class. MLP/QKV are AT rate; K=1024 is the
//    structural limit (128p-8ph measured worse, BK=128 exceeds LDS).
//  - gemm64 @ 4 blocks/CU: ~430 TF; best known for N=1024 K=1024 (proj).
//  - atomicAdd split-K: +75us contention (R7). Partial buffers instead.
//  - Concentrated on-device trig in an epilogue: +35us (R12); rope table fixed.
//  - R15: attn had ZERO load/compute overlap (syncthreads drains vmcnt(0)
//    every kv-iter == the m97 stall). Now double-buffered K/V + counted
//    vmcnt(4): tile t+1 in flight under compute(t). WAR-safe by the same
//    barrier-retires-reads construction as the GEMM engines.
//  - gemm256_mlp is the cross-round clock CONTROL: unchanged since R10;
//    R5's 98us (vs 79) with identical counters = container clock variance.

#define STG_A(q, pb, kc) gl_lds16(A  + gAoff[q] + (kc), &sA[pb][(q) * 4096 + tid * 8])
#define STG_B(q, pb, kc) gl_lds16(Bt + gBoff[q] + (kc), &sB[pb][(q) * 4096 + tid * 8])

// swizzled fragment loads; cs0/cs1 are the pre-XORed k-half column offsets
#define LDA(mh, m, h) (*(const bf16x8*)(cA + aRow + (mh) * 8192 + (m) * 2048 + (h)))
#define LDB(nh, n, h) (*(const bf16x8*)(cB + bRow + (nh) * 4096 + (n) * 2048 + (h)))

#define MFMA_QUAD(MH, NH, BF)                                                             \
    __builtin_amdgcn_s_setprio(1);                                                        \
    _Pragma("unroll")                                                                     \
    for (int m = 0; m < 4; ++m) {                                                         \
        _Pragma("unroll")                                                                 \
        for (int n = 0; n < 2; ++n) {                                                     \
            acc[(MH)*4+m][(NH)*2+n] = __builtin_amdgcn_mfma_f32_16x16x32_bf16(            \
                aF[m][0], BF[n][0], acc[(MH)*4+m][(NH)*2+n], 0, 0, 0);                    \
            acc[(MH)*4+m][(NH)*2+n] = __builtin_amdgcn_mfma_f32_16x16x32_bf16(            \
                aF[m][1], BF[n][1], acc[(MH)*4+m][(NH)*2+n], 0, 0, 0);                    \
        }                                                                                 \
    }                                                                                     \
    __builtin_amdgcn_s_setprio(0);

// 8-phase K-loop (256x256). Staging WAR-safe by barrier construction:
//  P2: A units 0,2 (last read P1), P3: all B (last read P2), P4: A units 1,3
//  (last read P3). One counted vmcnt(8) per K-tile; raw s_barrier throughout.
#define GEMM256_LOOP                                                                      \
    const int nt = K >> 6;                                                                \
    for (int t = 0; t < nt; ++t) {                                                        \
        const int pb = t & 1;                                                             \
        const char* cA = (const char*)sA[pb];                                             \
        const char* cB = (const char*)sB[pb];                                             \
        const int kc2 = (t + 2) << 6;                                                     \
        const bool pf = (t + 2) < nt;                                                     \
        bf16x8 aF[4][2], b0F[2][2], b1F[2][2];                                            \
        /* P1: read A-mh0 (8) + B-nh0 (4); MFMA (0,0) */                                  \
        _Pragma("unroll")                                                                 \
        for (int m = 0; m < 4; ++m) {                                                     \
            aF[m][0] = LDA(0, m, cs0);                                                    \
            aF[m][1] = LDA(0, m, cs1);                                                    \
        }                                                                                 \
        _Pragma("unroll")                                                                 \
        for (int n = 0; n < 2; ++n) {                                                     \
            b0F[n][0] = LDB(0, n, cs0);                                                   \
            b0F[n][1] = LDB(0, n, cs1);                                                   \
        }                                                                                 \
        __builtin_amdgcn_s_barrier();                                                     \
        asm volatile("s_waitcnt lgkmcnt(0)" ::: "memory");                                \
        MFMA_QUAD(0, 0, b0F)                                                              \
        __builtin_amdgcn_s_barrier();                                                     \
        /* P2: read B-nh1 (4); prefetch A units 0,2 of t+2; MFMA (0,1) */                 \
        _Pragma("unroll")                                                                 \
        for (int n = 0; n < 2; ++n) {                                                     \
            b1F[n][0] = LDB(1, n, cs0);                                                   \
            b1F[n][1] = LDB(1, n, cs1);                                                   \
        }                                                                                 \
        if (pf) { STG_A(0, pb, kc2); STG_A(2, pb, kc2); }                                 \
        __builtin_amdgcn_s_barrier();                                                     \
        asm volatile("s_waitcnt lgkmcnt(0)" ::: "memory");                                \
        MFMA_QUAD(0, 1, b1F)                                                              \
        __builtin_amdgcn_s_barrier();                                                     \
        /* P3: read A-mh1 (8); prefetch all B of t+2; MFMA (1,1) */                       \
        _Pragma("unroll")                                                                 \
        for (int m = 0; m < 4; ++m) {                                                     \
            aF[m][0] = LDA(1, m, cs0);                                                    \
            aF[m][1] = LDA(1, m, cs1);                                                    \
        }                                                                                 \
        if (pf) { STG_B(0, pb, kc2); STG_B(1, pb, kc2);                                   \
                  STG_B(2, pb, kc2); STG_B(3, pb, kc2); }                                 \
        __builtin_amdgcn_s_barrier();                                                     \
        asm volatile("s_waitcnt lgkmcnt(0)" ::: "memory");                                \
        MFMA_QUAD(1, 1, b1F)                                                              \
        __builtin_amdgcn_s_barrier();                                                     \
        /* P4: prefetch A units 1,3; MFMA (1,0); counted vmcnt */                         \
        if (pf) { STG_A(1, pb, kc2); STG_A(3, pb, kc2); }                                 \
        __builtin_amdgcn_s_barrier();                                                     \
        asm volatile("s_waitcnt lgkmcnt(0)" ::: "memory");                                \
        MFMA_QUAD(1, 0, b0F)                                                              \
        if (pf)              { asm volatile("s_waitcnt vmcnt(8)" ::: "memory"); }         \
        else if (t + 1 < nt) { asm volatile("s_waitcnt vmcnt(0)" ::: "memory"); }         \
        __builtin_amdgcn_s_barrier();                                                     \
    }

// shared block-index setup for the 256-wide engines
#define GEMM256_PROLOG(NPN, N0MUL)                                                        \
    const int tid = threadIdx.x;                                                          \
    const int wave = tid >> 6, lane = tid & 63;                                           \
    const int wr = wave >> 2, wc = wave & 3;                                              \
    const int cl = lane & 15, qd = lane >> 4;                                             \
    const int num_pid_n = (NPN);                                                          \
    const int cpx = gridDim.x >> 3;                                                       \
    int wg = (blockIdx.x & 7) * cpx + (blockIdx.x >> 3);                                  \
    const int group_size = 8 * num_pid_n;                                                 \
    const int group_id = wg / group_size;                                                 \
    const int pid_in = wg - group_id * group_size;                                        \
    const int m0 = (group_id * 8 + (pid_in & 7)) * 256;                                   \
    const int n0 = (pid_in >> 3) * (N0MUL);

// ---- merged prep: rope table + 4 weight transposes + emb GEMM (1 dispatch) --
// block ranges: [0,64) ropetab | [64,16448) transposes | [16448,16832) embgemm.
__global__ __launch_bounds__(256) void prep_kernel(
    float4* __restrict__ tab,
    const float* __restrict__ W0, bf16* __restrict__ T0,
    const float* __restrict__ W1, bf16* __restrict__ T1,
    const float* __restrict__ W2, bf16* __restrict__ T2,
    const float* __restrict__ W3, bf16* __restrict__ T3,
    const float* __restrict__ emb,
    const float* __restrict__ gW, const float* __restrict__ gb,
    const float* __restrict__ l1W, const float* __restrict__ l1b,
    const float* __restrict__ l2W, const float* __restrict__ l2b,
    float* __restrict__ G, float* __restrict__ SS, float* __restrict__ SS2)
{
    __shared__ float tile[32][33];
    __shared__ float se[256];
    int id = blockIdx.x;
    if (id < 64) {
        // rope cos/sin table: tab[s][j] = (cos0,sin0,cos1,sin1), freqs (j, j+16)
        int idx = id * 256 + threadIdx.x;   // 0..16383
        int s = idx >> 4, j = idx & 15;
        float inv0 = exp2f(-(float)j        * (13.287712379549449f / 32.f));
        float inv1 = exp2f(-(float)(16 + j) * (13.287712379549449f / 32.f));
        float sn0, c0, sn1, c1;
        sincosf((float)s * inv0, &sn0, &c0);
        sincosf((float)s * inv1, &sn1, &c1);
        tab[idx] = make_float4(c0, sn0, c1, sn1);
        return;
    }
    if (id < 16448) {
        id -= 64;
        const float* W; bf16* T; int K, N, bx, by;
        if (id < 3072)       { W = W0; T = T0; K = 1024; N = 3072; bx = id % 96;  by = id / 96; }
        else if (id < 4096)  { id -= 3072;  W = W1; T = T1; K = 1024; N = 1024; bx = id & 31;  by = id >> 5; }
        else if (id < 12288) { id -= 4096;  W = W2; T = T2; K = 1024; N = 8192; bx = id & 255; by = id >> 8; }
        else                 { id -= 12288; W = W3; T = T3; K = 4096; N = 1024; bx = id & 31;  by = id >> 5; }
        int n0 = bx * 32, k0 = by * 32;
        int tx = threadIdx.x & 31, ty = threadIdx.x >> 5;
        #pragma unroll
        for (int r = ty; r < 32; r += 8)
            tile[r][tx] = W[(long)(k0 + r) * N + n0 + tx];
        __syncthreads();
        #pragma unroll
        for (int r = ty; r < 32; r += 8)
            T[(long)(n0 + r) * K + k0 + tx] = __float2bfloat16(tile[tx][r]);
        return;
    }
    // embgemm: 384 blocks, decoded as (x=24, y=4, z=4)
    id -= 16448;
    int bx = id % 24, b = (id / 24) & 3, k0 = (id / 96) * 256;
    if (threadIdx.x < 256) se[threadIdx.x] = emb[b * 1024 + k0 + threadIdx.x];
    __syncthreads();
    int j = bx * 256 + threadIdx.x;   // 0..6143
    int which = j >> 11, col = j & 2047;
    const float* W  = which == 0 ? gW : (which == 1 ? l1W : l2W);
    const float* bb = which == 0 ? gb : (which == 1 ? l1b : l2b);
    float acc = (k0 == 0) ? bb[col] : 0.f;
    #pragma unroll 4
    for (int k = 0; k < 256; ++k) acc += se[k] * W[(long)(k0 + k) * 2048 + col];
    float* out = which == 0 ? G : (which == 1 ? SS : SS2);
    atomicAdd(&out[b * 2048 + col], acc);
}

// ---------------- rms_norm(x,w)*(1+ss[:D]) + ss[D:] -> bf16 ----------------
__global__ __launch_bounds__(256) void rmsmod_kernel(
    const float* __restrict__ x, const float* __restrict__ w,
    const float* __restrict__ ss, bf16* __restrict__ out)
{
    int row = blockIdx.x;        // 0..4095  (b*S + s)
    int b = row >> 10;
    const float* xr = x + (long)row * D_;
    float4 v = ((const float4*)xr)[threadIdx.x];
    float ssum = v.x * v.x + v.y * v.y + v.z * v.z + v.w * v.w;
    #pragma unroll
    for (int off = 32; off; off >>= 1) ssum += __shfl_xor(ssum, off);
    __shared__ float red[4];
    if ((threadIdx.x & 63) == 0) red[threadIdx.x >> 6] = ssum;
    __syncthreads();
    float tot = red[0] + red[1] + red[2] + red[3];
    float n = sqrtf(tot) * (1.f / 32.f);    // / sqrt(1024)
    float inv = 1.f / (n + 1e-6f);
    int d0 = threadIdx.x * 4;
    const float* ssb = ss + b * 2048;
    bf16 t[4];
    t[0] = __float2bfloat16(v.x * inv * w[d0 + 0] * (1.f + ssb[d0 + 0]) + ssb[D_ + d0 + 0]);
    t[1] = __float2bfloat16(v.y * inv * w[d0 + 1] * (1.f + ssb[d0 + 1]) + ssb[D_ + d0 + 1]);
    t[2] = __float2bfloat16(v.z * inv * w[d0 + 2] * (1.f + ssb[d0 + 2]) + ssb[D_ + d0 + 2]);
    t[3] = __float2bfloat16(v.w * inv * w[d0 + 3] * (1.f + ssb[d0 + 3]) + ssb[D_ + d0 + 3]);
    *(uint2*)&out[(long)row * D_ + d0] = *(uint2*)t;
}

// ------ QKV 256x256 engine with fused bias + rope + head-RMS + layout --------
__global__ __launch_bounds__(512) void qkvgemm_kernel(
    const bf16* __restrict__ A, const bf16* __restrict__ Bt,
    const float* __restrict__ bias,
    const float* __restrict__ nq_w, const float* __restrict__ nk_w,
    const float4* __restrict__ ropetab,
    bf16* __restrict__ qh, bf16* __restrict__ kh, bf16* __restrict__ vt,
    int N, int K)
{
    __shared__ bf16 sA[2][16384];
    __shared__ bf16 sB[2][16384];
    GEMM256_PROLOG(N >> 8, 256)

    long gAoff[4], gBoff[4];
    #pragma unroll
    for (int q = 0; q < 4; ++q) {
        int c = tid + q * 512;
        int cs = c ^ ((c >> 3) & 7);             // inverse of ((row&7)<<4) byte-XOR
        int row = cs >> 3, col = (cs & 7) * 8;
        gAoff[q] = (long)(m0 + row) * K + col;
        gBoff[q] = (long)(n0 + row) * K + col;
    }

    #pragma unroll
    for (int q = 0; q < 4; ++q) { STG_A(q, 0, 0); STG_B(q, 0, 0); }
    #pragma unroll
    for (int q = 0; q < 4; ++q) { STG_A(q, 1, 64); STG_B(q, 1, 64); }

    f32x4 acc[8][4] = {};
    const int swz = (cl & 7) << 4;               // lane-constant bank swizzle
    const int aRow = (wr * 128 + cl) * 128;
    const int bRow = (wc * 64 + cl) * 128;
    const int cs0 = (qd * 16) ^ swz;
    const int cs1 = (qd * 16 + 64) ^ swz;

    asm volatile("s_waitcnt vmcnt(8)" ::: "memory");
    __builtin_amdgcn_s_barrier();

    GEMM256_LOOP

    // ---- fused epilogue ----
    const int third = n0 >> 10;                  // 0=Q, 1=K, 2=V
    const int h = ((n0 & 1023) >> 6) + wc;       // head
    const int b = m0 >> 10;
    const int s0 = (m0 & 1023) + wr * 128;
    const int colb = n0 + wc * 64;
    float bs0 = bias[colb + cl],      bs1 = bias[colb + 16 + cl];
    float bs2 = bias[colb + 32 + cl], bs3 = bias[colb + 48 + cl];

    if (third == 2) {
        // V: bias + transpose-free packed stores: vt[(b*16+h)*64+d][s]
        #pragma unroll
        for (int n = 0; n < 4; ++n) {
            int d = n * 16 + cl;
            float bs = bias[colb + n * 16 + cl];
            long rowd = ((long)(b * 16 + h) * 64 + d) * 1024;
            #pragma unroll
            for (int m = 0; m < 8; ++m) {
                int sb = s0 + m * 16 + qd * 4;
                bf16 t4[4];
                #pragma unroll
                for (int i = 0; i < 4; ++i)
                    t4[i] = __float2bfloat16(acc[m][n][i] + bs);
                *(uint2*)&vt[rowd + sb] = *(uint2*)t4;
            }
        }
    } else {
        const float* w = (third == 0) ? nq_w : nk_w;
        bf16* dst = (third == 0) ? qh : kh;
        float w0 = w[cl], w1 = w[16 + cl], w2 = w[32 + cl], w3 = w[48 + cl];
        long hb = ((long)(b * 16 + h) * 1024) * 64;
        #pragma unroll
        for (int m = 0; m < 8; ++m) {
            #pragma unroll
            for (int i = 0; i < 4; ++i) {
                int s = s0 + m * 16 + qd * 4 + i;
                float v0 = acc[m][0][i] + bs0, v1 = acc[m][1][i] + bs1;
                float v2 = acc[m][2][i] + bs2, v3 = acc[m][3][i] + bs3;
                float4 cs = ropetab[s * 16 + cl];   // (cos0,sin0,cos1,sin1)
                float r0 = v0 * cs.x - v2 * cs.y;
                float r1 = v1 * cs.z - v3 * cs.w;
                float r2 = v2 * cs.x + v0 * cs.y;
                float r3 = v3 * cs.z + v1 * cs.w;
                float ssq = r0 * r0 + r1 * r1 + r2 * r2 + r3 * r3;
                ssq += __shfl_xor(ssq, 1);
                ssq += __shfl_xor(ssq, 2);
                ssq += __shfl_xor(ssq, 4);
                ssq += __shfl_xor(ssq, 8);
                float innv = 1.f / (sqrtf(ssq) * 0.125f + 1e-6f);   // /sqrt(64)
                long ro = hb + (long)s * 64;
                dst[ro + cl]      = __float2bfloat16(r0 * innv * w0);
                dst[ro + 16 + cl] = __float2bfloat16(r1 * innv * w1);
                dst[ro + 32 + cl] = __float2bfloat16(r2 * innv * w2);
                dst[ro + 48 + cl] = __float2bfloat16(r3 * innv * w3);
            }
        }
    }
}

// -------- fused MLP 256-engine: h = A @ Wt^T + b; ACT = h1 * silu(h2) --------
__global__ __launch_bounds__(512) void gemm256_mlp_kernel(
    const bf16* __restrict__ A, const bf16* __restrict__ Bt,
    const float* __restrict__ bias, bf16* __restrict__ ACT, int K)
{
    __shared__ bf16 sA[2][16384];
    __shared__ bf16 sB[2][16384];
    GEMM256_PROLOG(32, 128)

    long gAoff[4], gBoff[4];
    #pragma unroll
    for (int q = 0; q < 4; ++q) {
        int c = tid + q * 512;
        int cs = c ^ ((c >> 3) & 7);
        int row = cs >> 3, col = (cs & 7) * 8;
        gAoff[q] = (long)(m0 + row) * K + col;
        int pp = row >> 5, hf = (row >> 4) & 1, wi = row & 15;
        gBoff[q] = (long)(hf * 4096 + n0 + pp * 16 + wi) * K + col;
    }

    #pragma unroll
    for (int q = 0; q < 4; ++q) { STG_A(q, 0, 0); STG_B(q, 0, 0); }
    #pragma unroll
    for (int q = 0; q < 4; ++q) { STG_A(q, 1, 64); STG_B(q, 1, 64); }

    f32x4 acc[8][4] = {};
    const int swz = (cl & 7) << 4;
    const int aRow = (wr * 128 + cl) * 128;
    const int bRow = (wc * 64 + cl) * 128;
    const int cs0 = (qd * 16) ^ swz;
    const int cs1 = (qd * 16 + 64) ^ swz;

    asm volatile("s_waitcnt vmcnt(8)" ::: "memory");
    __builtin_amdgcn_s_barrier();

    GEMM256_LOOP

    #pragma unroll
    for (int m = 0; m < 8; ++m) {
        #pragma unroll
        for (int pr = 0; pr < 2; ++pr) {
            int col = n0 + wc * 32 + pr * 16 + cl;
            float bs1 = bias[col];
            float bs2 = bias[4096 + col];
            #pragma unroll
            for (int i = 0; i < 4; ++i) {
                int row = m0 + wr * 128 + m * 16 + qd * 4 + i;
                float h1 = acc[m][pr * 2 + 0][i] + bs1;
                float h2 = acc[m][pr * 2 + 1][i] + bs2;
                float sg = 1.f / (1.f + __expf(-h2));
                ACT[(long)row * 4096 + col] = __float2bfloat16(h1 * h2 * sg);
            }
        }
    }
}

// ------- 256x128 / BK=64 split-K=2 engine (out-proj: N=1024, K=4096) ---------
#define MFMA_HQ(MH)                                                                       \
    __builtin_amdgcn_s_setprio(1);                                                        \
    _Pragma("unroll")                                                                     \
    for (int m = 0; m < 4; ++m) {                                                         \
        _Pragma("unroll")                                                                 \
        for (int n = 0; n < 2; ++n) {                                                     \
            acc[(MH)*4+m][n] = __builtin_amdgcn_mfma_f32_16x16x32_bf16(                   \
                aF[m][0], bF[n][0], acc[(MH)*4+m][n], 0, 0, 0);                           \
            acc[(MH)*4+m][n] = __builtin_amdgcn_mfma_f32_16x16x32_bf16(                   \
                aF[m][1], bF[n][1], acc[(MH)*4+m][n], 0, 0, 0);                           \
        }                                                                                 \
    }                                                                                     \
    __builtin_amdgcn_s_setprio(0);

__global__ __launch_bounds__(512) void gemm256x128_kernel(
    const bf16* __restrict__ A, const bf16* __restrict__ Bt,
    float* __restrict__ P0, float* __restrict__ P1, int N, int K)
{
    __shared__ bf16 sA[2][16384];
    __shared__ bf16 sB[2][8192];
    const int tid = threadIdx.x;
    const int wave = tid >> 6, lane = tid & 63;
    const int wr = wave >> 2, wc = wave & 3;
    const int cl = lane & 15, qd = lane >> 4;

    const int cpx = gridDim.x >> 3;                 // 256 blocks: %8==0 bijective
    int wg = (blockIdx.x & 7) * cpx + (blockIdx.x >> 3);
    const int split = wg >> 7;                      // K-half
    const int w2 = wg & 127;                        // 16 m-tiles x 8 n-tiles
    const int group_id = w2 >> 6;
    const int pid_in = w2 & 63;
    const int m0 = (group_id * 8 + (pid_in & 7)) * 256;
    const int n0 = (pid_in >> 3) * 128;
    const int Kh = K >> 1;
    A  += (long)split * Kh;
    Bt += (long)split * Kh;

    long gAoff[4], gBoff[2];
    #pragma unroll
    for (int q = 0; q < 4; ++q) {
        int c = tid + q * 512;
        int cs = c ^ ((c >> 3) & 7);
        int row = cs >> 3, col = (cs & 7) * 8;
        gAoff[q] = (long)(m0 + row) * K + col;
        if (q < 2) gBoff[q] = (long)(n0 + row) * K + col;
    }

    const int nt = Kh >> 6;
    // prologue: X+B(0), Y(0), X+B(1)
    STG_A(0, 0, 0); STG_A(2, 0, 0); STG_B(0, 0, 0); STG_B(1, 0, 0);
    STG_A(1, 0, 0); STG_A(3, 0, 0);
    if (nt > 1) { STG_A(0, 1, 64); STG_A(2, 1, 64); STG_B(0, 1, 64); STG_B(1, 1, 64); }

    f32x4 acc[8][2] = {};
    const int swz = (cl & 7) << 4;
    const int aRow = (wr * 128 + cl) * 128;
    const int bRow = (wc * 32 + cl) * 128;
    const int cs0 = (qd * 16) ^ swz;
    const int cs1 = (qd * 16 + 64) ^ swz;

    if (nt > 1) { asm volatile("s_waitcnt vmcnt(4)" ::: "memory"); }
    else        { asm volatile("s_waitcnt vmcnt(0)" ::: "memory"); }
    __builtin_amdgcn_s_barrier();

    for (int t = 0; t < nt; ++t) {
        const int pb = t & 1;
        const char* cA = (const char*)sA[pb];
        const char* cB = (const char*)sB[pb];
        bf16x8 aF[4][2], bF[2][2];
        // P1: read A-mh0 (8) + B (4); stage Y(t+1) -> buf[pb^1]
        #pragma unroll
        for (int m = 0; m < 4; ++m) {
            aF[m][0] = *(const bf16x8*)(cA + aRow + m * 2048 + cs0);
            aF[m][1] = *(const bf16x8*)(cA + aRow + m * 2048 + cs1);
        }
        #pragma unroll
        for (int n = 0; n < 2; ++n) {
            bF[n][0] = *(const bf16x8*)(cB + bRow + n * 2048 + cs0);
            bF[n][1] = *(const bf16x8*)(cB + bRow + n * 2048 + cs1);
        }
        if (t + 1 < nt) { STG_A(1, pb ^ 1, (t + 1) << 6); STG_A(3, pb ^ 1, (t + 1) << 6); }
        __builtin_amdgcn_s_barrier();
        asm volatile("s_waitcnt lgkmcnt(0)" ::: "memory");
        MFMA_HQ(0)
        __builtin_amdgcn_s_barrier();
        // P2: read A-mh1 (8); stage X+B(t+2) -> buf[pb]
        #pragma unroll
        for (int m = 0; m < 4; ++m) {
            aF[m][0] = *(const bf16x8*)(cA + aRow + 8192 + m * 2048 + cs0);
            aF[m][1] = *(const bf16x8*)(cA + aRow + 8192 + m * 2048 + cs1);
        }
        if (t + 2 < nt) { STG_A(0, pb, (t + 2) << 6); STG_A(2, pb, (t + 2) << 6);
                          STG_B(0, pb, (t + 2) << 6); STG_B(1, pb, (t + 2) << 6); }
        __builtin_amdgcn_s_barrier();
        asm volatile("s_waitcnt lgkmcnt(0)" ::: "memory");
        MFMA_HQ(1)
        if (t + 2 < nt)      { asm volatile("s_waitcnt vmcnt(4)" ::: "memory"); }
        else if (t + 1 < nt) { asm volatile("s_waitcnt vmcnt(0)" ::: "memory"); }
        __builtin_amdgcn_s_barrier();
    }

    float* P = split ? P1 : P0;
    #pragma unroll
    for (int m = 0; m < 8; ++m) {
        #pragma unroll
        for (int n = 0; n < 2; ++n) {
            int col = n0 + wc * 32 + n * 16 + cl;
            #pragma unroll
            for (int i = 0; i < 4; ++i) {
                int row = m0 + wr * 128 + m * 16 + qd * 4 + i;
                P[(long)row * N + col] = acc[m][n][i];
            }
        }
    }
}

// ------- fuse: out = X1 + gate_mlp * (p0 + p1 + bias)  (float4) --------------
__global__ __launch_bounds__(256) void fuseout_kernel(
    const float* __restrict__ p0, const float* __restrict__ p1,
    const float* __restrict__ bias, const float* __restrict__ resid,
    const float* __restrict__ gates, float* __restrict__ out)
{
    int idx = blockIdx.x * 256 + threadIdx.x;     // over 4096*1024/4
    int row = idx >> 8;
    int b = row >> 10;
    int c4 = (idx & 255) * 4;
    float4 a = ((const float4*)p0)[idx];
    float4 c = ((const float4*)p1)[idx];
    float4 r = ((const float4*)resid)[idx];
    float4 bb = *(const float4*)&bias[c4];
    float4 gg = *(const float4*)&gates[b * 2048 + 1024 + c4];
    float4 o;
    o.x = r.x + gg.x * (a.x + c.x + bb.x);
    o.y = r.y + gg.y * (a.y + c.y + bb.y);
    o.z = r.z + gg.z * (a.z + c.z + bb.z);
    o.w = r.w + gg.w * (a.w + c.w + bb.w);
    ((float4*)out)[idx] = o;
}

// ---------------- 64x64-tile bf16 MFMA GEMM (proj; R5-proven best) -----------
__global__ __launch_bounds__(256) void gemm64_kernel(
    const bf16* __restrict__ A, const bf16* __restrict__ Bt,
    const float* __restrict__ bias,
    bf16* __restrict__ Cb, float* __restrict__ Cf,
    const float* __restrict__ resid, const float* __restrict__ gates, int gate_off,
    int Mrows, int N, int K, int mode)
{
    __shared__ bf16 sA[64 * 32];
    __shared__ bf16 sB[64 * 32];
    const int tid = threadIdx.x;
    const int wave = tid >> 6, lane = tid & 63;
    const int num_pid_n = N >> 6;
    const int pid = blockIdx.x;
    const int group_size = 8 * num_pid_n;
    const int group_id = pid / group_size;
    const int pid_in = pid - group_id * group_size;
    const int pid_m = group_id * 8 + (pid_in & 7);
    const int pid_n = pid_in >> 3;
    const int m0 = pid_m * 64, n0 = pid_n * 64;
    const int wm = (wave & 1) * 32, wn = (wave >> 1) * 32;
    const int cl = lane & 15, qd = lane >> 4;

    f32x4 acc[2][2] = {};

    const int c = tid;
    const int rr = c >> 2, ss = (c & 3) ^ ((c >> 3) & 3);
    const bf16* gA = A + (long)(m0 + rr) * K + ss * 8;
    const bf16* gB = Bt + (long)(n0 + rr) * K + ss * 8;
    bf16* lA = &sA[wave * 512];
    bf16* lB = &sB[wave * 512];

    const int q8s = (qd ^ ((cl >> 1) & 3)) * 8;

    for (int kc = 0; kc < K; kc += 32) {
        gl_lds16(gA + kc, lA);
        gl_lds16(gB + kc, lB);
        __syncthreads();
        bf16x8 af[2], bfr[2];
        #pragma unroll
        for (int t = 0; t < 2; ++t)
            af[t] = *(const bf16x8*)&sA[(wm + cl + t * 16) * 32 + q8s];
        #pragma unroll
        for (int u = 0; u < 2; ++u)
            bfr[u] = *(const bf16x8*)&sB[(wn + cl + u * 16) * 32 + q8s];
        #pragma unroll
        for (int t = 0; t < 2; ++t)
            #pragma unroll
            for (int u = 0; u < 2; ++u)
                acc[t][u] = __builtin_amdgcn_mfma_f32_16x16x32_bf16(af[t], bfr[u], acc[t][u], 0, 0, 0);
        __syncthreads();
    }

    #pragma unroll
    for (int t = 0; t < 2; ++t) {
        #pragma unroll
        for (int u = 0; u < 2; ++u) {
            int col = n0 + wn + u * 16 + cl;
            float bs = bias[col];
            #pragma unroll
            for (int i = 0; i < 4; ++i) {
                int row = m0 + wm + t * 16 + qd * 4 + i;
                float v = acc[t][u][i] + bs;
                if (mode == 0) {
                    Cb[(long)row * N + col] = __float2bfloat16(v);
                } else {
                    int b = row >> 10;
                    float g = gates[b * 2048 + gate_off + col];
                    Cf[(long)row * N + col] = resid[(long)row * N + col] + g * v;
                }
            }
        }
    }
}

// ---------------- fused flash-style attention, fixed-shift softmax ------------
// Q,K rows are RMS-normalized (unit weights) -> ||q||=||k||=8, so by
// Cauchy-Schwarz scores = q.k/8 are in [-8, 8]. Softmax is shift-invariant:
// use fixed shift 8 instead of online running max.
// R14: linear [64][128B] LDS tiles + R9 XOR swizzle, gl_lds w/ pre-swizzled src.
// R15: double-buffered K/V + counted vmcnt(4) -- tile t+1's loads stay in
// flight under compute(t) (T3/T4 applied to attn; was vmcnt(0)-drained every
// iter). WAR-safe: buf[(t+1)&1] was last read in compute(t-1), whose ds_reads
// retire (lgkm-waited before their MFMAs) before any wave passes iter t's
// first barrier.
__global__ __launch_bounds__(256) void attn_kernel(
    const bf16* __restrict__ qh, const bf16* __restrict__ kh, const bf16* __restrict__ vt,
    bf16* __restrict__ ao)
{
    const int bh = blockIdx.y;
    const int q0 = blockIdx.x * 64;
    const int tid = threadIdx.x, wave = tid >> 6, lane = tid & 63;
    const int cl = lane & 15, qd = lane >> 4;

    __shared__ bf16 sQ[64 * 64];
    __shared__ bf16 sK[2][64 * 64];
    __shared__ bf16 sV[2][64 * 64];
    __shared__ bf16 sP[4][16 * 64];

    // staging geometry: thread a -> row = a>>3, source chunk = (a&7)^(row&7),
    // LDS dest linear a*16 bytes (gl_lds requirement).
    const int r0 = tid >> 3;
    const int c0 = (tid & 7) ^ (r0 & 7);
    const int r1 = (tid + 256) >> 3;
    const int c1 = ((tid + 256) & 7) ^ (r1 & 7);

    const bf16* Kg = kh + (long)bh * S_ * 64;
    const bf16* Vg = vt + (long)bh * 64 * S_;

    #define ATTN_STAGE(t) {                                                          \
        int kv = (t) * 64;                                                           \
        gl_lds16(Kg + (long)(kv + r0) * 64 + c0 * 8, &sK[(t) & 1][(long)tid * 8]);   \
        gl_lds16(Kg + (long)(kv + r1) * 64 + c1 * 8, &sK[(t) & 1][(long)(tid + 256) * 8]); \
        gl_lds16(Vg + (long)r0 * S_ + kv + c0 * 8, &sV[(t) & 1][(long)tid * 8]);     \
        gl_lds16(Vg + (long)r1 * S_ + kv + c1 * 8, &sV[(t) & 1][(long)(tid + 256) * 8]); }

    {   // prologue: stage Q tile + K/V tile 0
        const bf16* Qg = qh + (long)bh * S_ * 64 + (long)q0 * 64;
        gl_lds16(Qg + r0 * 64 + c0 * 8, &sQ[(long)tid * 8]);
        gl_lds16(Qg + r1 * 64 + c1 * 8, &sQ[(long)(tid + 256) * 8]);
        ATTN_STAGE(0)
    }

    float l_i[4] = {0.f, 0.f, 0.f, 0.f};
    f32x4 o_acc[4] = {};

    const int swz = (cl & 7) << 4;               // lane-constant read XOR
    const char* cQ = (const char*)sQ;
    char* cP = (char*)sP[wave];
    const int aqRow = (wave * 16 + cl) * 128;

    for (int t = 0; t < 16; ++t) {
        __builtin_amdgcn_s_barrier();            // all waves done reading buf[(t+1)&1]
        if (t + 1 < 16) {
            ATTN_STAGE(t + 1)                    // 4 loads in flight across compute(t)
            asm volatile("s_waitcnt vmcnt(4)" ::: "memory");   // tile t (and Q) landed
        } else {
            asm volatile("s_waitcnt vmcnt(0)" ::: "memory");
        }
        __builtin_amdgcn_s_barrier();            // tile t visible to all waves
        const char* cK = (const char*)sK[t & 1];
        const char* cV = (const char*)sV[t & 1];

        // S = Q_wave (16 x 64) @ K_tile^T  -> 4 col-tiles of 16
        f32x4 sfr[4] = {};
        #pragma unroll
        for (int ks = 0; ks < 2; ++ks) {
            const int co = (ks * 64 + qd * 16) ^ swz;
            bf16x8 aq = *(const bf16x8*)(cQ + aqRow + co);
            #pragma unroll
            for (int u = 0; u < 4; ++u) {
                bf16x8 bk = *(const bf16x8*)(cK + (u * 16 + cl) * 128 + co);
                sfr[u] = __builtin_amdgcn_mfma_f32_16x16x32_bf16(aq, bk, sfr[u], 0, 0, 0);
            }
        }

        // fixed-shift softmax: p = exp(s*0.125 - 8), accumulate l_i
        #pragma unroll
        for (int i = 0; i < 4; ++i) {
            int rowp = qd * 4 + i;
            char* pb = cP + rowp * 128;
            const int xorv = (rowp & 7) << 4;
            float sum = 0.f;
            #pragma unroll
            for (int u = 0; u < 4; ++u) {
                float p = __expf(sfr[u][i] * 0.125f - 8.f);
                sum += p;
                *(bf16*)(pb + ((u * 32 + cl * 2) ^ xorv)) = __float2bfloat16(p);
            }
            sum += __shfl_xor(sum, 1);
            sum += __shfl_xor(sum, 2);
            sum += __shfl_xor(sum, 4);
            sum += __shfl_xor(sum, 8);
            l_i[i] += sum;
        }

        // O += P (16 x 64kv) @ V (64kv x 64d); P read back in A-layout from LDS
        #pragma unroll
        for (int ks = 0; ks < 2; ++ks) {
            const int co = (ks * 64 + qd * 16) ^ swz;
            bf16x8 ap = *(const bf16x8*)(cP + cl * 128 + co);
            #pragma unroll
            for (int u = 0; u < 4; ++u) {
                bf16x8 bv = *(const bf16x8*)(cV + (u * 16 + cl) * 128 + co);
                o_acc[u] = __builtin_amdgcn_mfma_f32_16x16x32_bf16(ap, bv, o_acc[u], 0, 0, 0);
            }
        }
    }
    #undef ATTN_STAGE

    // epilogue: ao[b, s, h*64+d]
    #pragma unroll
    for (int i = 0; i < 4; ++i) {
        float invl = 1.f / l_i[i];
        int row = q0 + wave * 16 + qd * 4 + i;
        #pragma unroll
        for (int u = 0; u < 4; ++u) {
            int d = u * 16 + cl;
            ao[((long)(bh >> 4) * S_ + row) * D_ + (bh & 15) * 64 + d] =
                __float2bfloat16(o_acc[u][i] * invl);
        }
    }
}

extern "C" void kernel_launch(void* const* d_in, const int* in_sizes, int n_in,
                              void* d_out, int out_size, void* d_ws, size_t ws_size,
                              hipStream_t stream) {
    const float* x       = (const float*)d_in[0];
    const float* emb     = (const float*)d_in[1];
    const float* ln1_w   = (const float*)d_in[2];
    const float* ln1_lW  = (const float*)d_in[3];
    const float* ln1_lb  = (const float*)d_in[4];
    const float* ln2_w   = (const float*)d_in[5];
    const float* ln2_lW  = (const float*)d_in[6];
    const float* ln2_lb  = (const float*)d_in[7];
    const float* qkv_W   = (const float*)d_in[8];
    const float* qkv_b   = (const float*)d_in[9];
    const float* proj_W  = (const float*)d_in[10];
    const float* proj_b  = (const float*)d_in[11];
    const float* nq_w    = (const float*)d_in[12];
    const float* nk_w    = (const float*)d_in[13];
    const float* mlp_W   = (const float*)d_in[14];
    const float* mlp_b   = (const float*)d_in[15];
    const float* out_W   = (const float*)d_in[16];
    const float* out_b   = (const float*)d_in[17];
    const float* gates_W = (const float*)d_in[18];
    const float* gates_b = (const float*)d_in[19];
    float* out = (float*)d_out;

    // workspace layout (all offsets 256B aligned)
    char* p = (char*)d_ws;
    if (ws_size < 159481856UL) return;  // loud failure rather than OOB corruption
    bf16* WT_QKV  = (bf16*)p;  p += 6291456;   // [3072][1024]
    bf16* WT_PROJ = (bf16*)p;  p += 2097152;   // [1024][1024]
    bf16* WT_MLP  = (bf16*)p;  p += 16777216;  // [8192][1024]
    bf16* WT_OUT  = (bf16*)p;  p += 8388608;   // [1024][4096]
    float* G      = (float*)p; p += 32768;     // [4][2048]
    float* SSb    = (float*)p; p += 32768;
    float* SS2b   = (float*)p; p += 32768;
    float* X1     = (float*)p; p += 16777216;  // f32 [4096][1024]
    bf16* XN2     = (bf16*)p;  p += 8388608;
    bf16* ACT     = (bf16*)p;  p += 33554432;  // [4096][4096]
    char* REG = p;                              // reused region
    bf16* XN   = (bf16*)(REG);
    bf16* QH   = (bf16*)(REG + 33554432);      // [B,H,S,HD]
    bf16* KH   = (bf16*)(REG + 41943040);
    bf16* VT   = (bf16*)(REG + 50331648);      // [B,H,HD,S]
    bf16* AO   = (bf16*)(REG + 58720256);      // [4096][1024]
    // split-K partials for the out-proj: reuse REG head (XN dead by then)
    float* PF0 = (float*)(REG);                // [4096][1024] f32
    float* PF1 = (float*)(REG + 16777216);
    // rope table: head of X1 (X1 is written only later by the proj GEMM)
    float4* ROPETAB = (float4*)X1;             // [1024][16] float4 = 256 KB

    dim3 blk(256);
    // zero G/SSb/SS2b (96 KB) for embgemm's atomicAdd k-split
    hipMemsetAsync(G, 0, 98304, stream);
    // merged prep: ropetab (64) + transposes (16384) + embgemm (384)
    prep_kernel<<<dim3(16832), blk, 0, stream>>>(ROPETAB,
                                                 qkv_W, WT_QKV, proj_W, WT_PROJ,
                                                 mlp_W, WT_MLP, out_W, WT_OUT,
                                                 emb, gates_W, gates_b, ln1_lW, ln1_lb,
                                                 ln2_lW, ln2_lb, G, SSb, SS2b);
    rmsmod_kernel<<<dim3(4096), blk, 0, stream>>>(x, ln1_w, SSb, XN);
    // QKV GEMM + fused bias/rope/head-norm/layout: M=4096 N=3072 K=1024
    qkvgemm_kernel<<<dim3(192), dim3(512), 0, stream>>>(XN, WT_QKV, qkv_b, nq_w, nk_w,
                                                        ROPETAB, QH, KH, VT, 3072, 1024);
    attn_kernel<<<dim3(16, 64), blk, 0, stream>>>(QH, KH, VT, AO);
    gemm64_kernel<<<dim3(1024), blk, 0, stream>>>(AO, WT_PROJ, proj_b, nullptr, X1,
                                                  x, G, 0, 4096, 1024, 1024, 1);
    rmsmod_kernel<<<dim3(4096), blk, 0, stream>>>(X1, ln2_w, SS2b, XN2);
    // fused MLP: 16 m-tiles x 32 fused col-tiles = 512 blocks
    gemm256_mlp_kernel<<<dim3(512), dim3(512), 0, stream>>>(XN2, WT_MLP, mlp_b, ACT, 1024);
    // out-proj: 256x128 split-K=2 engine (256 blocks = exact CU fill) + fuse
    gemm256x128_kernel<<<dim3(256), dim3(512), 0, stream>>>(ACT, WT_OUT, PF0, PF1, 1024, 4096);
    fuseout_kernel<<<dim3(4096), blk, 0, stream>>>(PF0, PF1, out_b, X1, G, out);
}

// Round 8
// 450.061 us; speedup vs baseline: 1.0064x; 1.0064x over previous
//
#include <hip/hip_runtime.h>
#include <hip/hip_bf16.h>
#include <math.h>

#define B_ 4
#define S_ 1024
#define D_ 1024
#define H_ 16
#define HD_ 64
#define M_ 4096
#define E_ 1024

using bf16 = __hip_bfloat16;
typedef short bf16x8 __attribute__((ext_vector_type(8)));
typedef float f32x4 __attribute__((ext_vector_type(4)));

__device__ __forceinline__ void gl_lds16(const void* g, void* l) {
    __builtin_amdgcn_global_load_lds(
        (__attribute__((address_space(1))) void*)(g),
        (__attribute__((address_space(3))) void*)(l), 16, 0, 0);
}

// LDS swizzle (R9, measured): physical = logical ^ ((row&7)<<4) on
// [rows][64 k-elem] bf16 tiles. Source pre-swizzle in 16B-chunk space:
// c ^= (row&7). Fragment-read XOR ((cl&7)<<4) lane-constant, hoisted.

// Engine lessons (R4-R16, measured):
//  - 256x256 8-phase + swizzle + counted vmcnt: 849 TF @ K=1024 == m248
//    reference rate. MLP/QKV GEMM cores are AT rate for this shape class.
//  - ERRATA (R16): R14's "8-way conflict" claim on attn's pad-72 layout was
//    WRONG -- start-bank 4*(cl+qd) mod 32 is UNIFORM (8 lanes/4-bank group =
//    the b128 floor). R14+R15 bought ~4us, not 30. Attn is occupancy/issue
//    bound, not LDS-bound.
//  - R16: attn LDS 48->40KB (Q in registers) => 4 blocks/CU, one full
//    resident pass of the 1024-block grid; + T5 setprio (attn-positive, m191).
//  - R16: qkvgemm Q/K epilogue had 128 scalar 2B stores/lane (G13 violation);
//    now LDS-bounce -> 2x16B coalesced stores per m.
//  - gemm256_mlp is the cross-round clock CONTROL (unchanged since R10).

#define STG_A(q, pb, kc) gl_lds16(A  + gAoff[q] + (kc), &sA[pb][(q) * 4096 + tid * 8])
#define STG_B(q, pb, kc) gl_lds16(Bt + gBoff[q] + (kc), &sB[pb][(q) * 4096 + tid * 8])

#define LDA(mh, m, h) (*(const bf16x8*)(cA + aRow + (mh) * 8192 + (m) * 2048 + (h)))
#define LDB(nh, n, h) (*(const bf16x8*)(cB + bRow + (nh) * 4096 + (n) * 2048 + (h)))

#define MFMA_QUAD(MH, NH, BF)                                                             \
    __builtin_amdgcn_s_setprio(1);                                                        \
    _Pragma("unroll")                                                                     \
    for (int m = 0; m < 4; ++m) {                                                         \
        _Pragma("unroll")                                                                 \
        for (int n = 0; n < 2; ++n) {                                                     \
            acc[(MH)*4+m][(NH)*2+n] = __builtin_amdgcn_mfma_f32_16x16x32_bf16(            \
                aF[m][0], BF[n][0], acc[(MH)*4+m][(NH)*2+n], 0, 0, 0);                    \
            acc[(MH)*4+m][(NH)*2+n] = __builtin_amdgcn_mfma_f32_16x16x32_bf16(            \
                aF[m][1], BF[n][1], acc[(MH)*4+m][(NH)*2+n], 0, 0, 0);                    \
        }                                                                                 \
    }                                                                                     \
    __builtin_amdgcn_s_setprio(0);

// 8-phase K-loop (256x256). Staging WAR-safe by barrier construction:
//  P2: A units 0,2 (last read P1), P3: all B (last read P2), P4: A units 1,3
//  (last read P3). One counted vmcnt(8) per K-tile; raw s_barrier throughout.
#define GEMM256_LOOP                                                                      \
    const int nt = K >> 6;                                                                \
    for (int t = 0; t < nt; ++t) {                                                        \
        const int pb = t & 1;                                                             \
        const char* cA = (const char*)sA[pb];                                             \
        const char* cB = (const char*)sB[pb];                                             \
        const int kc2 = (t + 2) << 6;                                                     \
        const bool pf = (t + 2) < nt;                                                     \
        bf16x8 aF[4][2], b0F[2][2], b1F[2][2];                                            \
        /* P1: read A-mh0 (8) + B-nh0 (4); MFMA (0,0) */                                  \
        _Pragma("unroll")                                                                 \
        for (int m = 0; m < 4; ++m) {                                                     \
            aF[m][0] = LDA(0, m, cs0);                                                    \
            aF[m][1] = LDA(0, m, cs1);                                                    \
        }                                                                                 \
        _Pragma("unroll")                                                                 \
        for (int n = 0; n < 2; ++n) {                                                     \
            b0F[n][0] = LDB(0, n, cs0);                                                   \
            b0F[n][1] = LDB(0, n, cs1);                                                   \
        }                                                                                 \
        __builtin_amdgcn_s_barrier();                                                     \
        asm volatile("s_waitcnt lgkmcnt(0)" ::: "memory");                                \
        MFMA_QUAD(0, 0, b0F)                                                              \
        __builtin_amdgcn_s_barrier();                                                     \
        /* P2: read B-nh1 (4); prefetch A units 0,2 of t+2; MFMA (0,1) */                 \
        _Pragma("unroll")                                                                 \
        for (int n = 0; n < 2; ++n) {                                                     \
            b1F[n][0] = LDB(1, n, cs0);                                                   \
            b1F[n][1] = LDB(1, n, cs1);                                                   \
        }                                                                                 \
        if (pf) { STG_A(0, pb, kc2); STG_A(2, pb, kc2); }                                 \
        __builtin_amdgcn_s_barrier();                                                     \
        asm volatile("s_waitcnt lgkmcnt(0)" ::: "memory");                                \
        MFMA_QUAD(0, 1, b1F)                                                              \
        __builtin_amdgcn_s_barrier();                                                     \
        /* P3: read A-mh1 (8); prefetch all B of t+2; MFMA (1,1) */                       \
        _Pragma("unroll")                                                                 \
        for (int m = 0; m < 4; ++m) {                                                     \
            aF[m][0] = LDA(1, m, cs0);                                                    \
            aF[m][1] = LDA(1, m, cs1);                                                    \
        }                                                                                 \
        if (pf) { STG_B(0, pb, kc2); STG_B(1, pb, kc2);                                   \
                  STG_B(2, pb, kc2); STG_B(3, pb, kc2); }                                 \
        __builtin_amdgcn_s_barrier();                                                     \
        asm volatile("s_waitcnt lgkmcnt(0)" ::: "memory");                                \
        MFMA_QUAD(1, 1, b1F)                                                              \
        __builtin_amdgcn_s_barrier();                                                     \
        /* P4: prefetch A units 1,3; MFMA (1,0); counted vmcnt */                         \
        if (pf) { STG_A(1, pb, kc2); STG_A(3, pb, kc2); }                                 \
        __builtin_amdgcn_s_barrier();                                                     \
        asm volatile("s_waitcnt lgkmcnt(0)" ::: "memory");                                \
        MFMA_QUAD(1, 0, b0F)                                                              \
        if (pf)              { asm volatile("s_waitcnt vmcnt(8)" ::: "memory"); }         \
        else if (t + 1 < nt) { asm volatile("s_waitcnt vmcnt(0)" ::: "memory"); }         \
        __builtin_amdgcn_s_barrier();                                                     \
    }

// shared block-index setup for the 256-wide engines
#define GEMM256_PROLOG(NPN, N0MUL)                                                        \
    const int tid = threadIdx.x;                                                          \
    const int wave = tid >> 6, lane = tid & 63;                                           \
    const int wr = wave >> 2, wc = wave & 3;                                              \
    const int cl = lane & 15, qd = lane >> 4;                                             \
    const int num_pid_n = (NPN);                                                          \
    const int cpx = gridDim.x >> 3;                                                       \
    int wg = (blockIdx.x & 7) * cpx + (blockIdx.x >> 3);                                  \
    const int group_size = 8 * num_pid_n;                                                 \
    const int group_id = wg / group_size;                                                 \
    const int pid_in = wg - group_id * group_size;                                        \
    const int m0 = (group_id * 8 + (pid_in & 7)) * 256;                                   \
    const int n0 = (pid_in >> 3) * (N0MUL);

// ---- merged prep: rope table + 4 weight transposes + emb GEMM (1 dispatch) --
__global__ __launch_bounds__(256) void prep_kernel(
    float4* __restrict__ tab,
    const float* __restrict__ W0, bf16* __restrict__ T0,
    const float* __restrict__ W1, bf16* __restrict__ T1,
    const float* __restrict__ W2, bf16* __restrict__ T2,
    const float* __restrict__ W3, bf16* __restrict__ T3,
    const float* __restrict__ emb,
    const float* __restrict__ gW, const float* __restrict__ gb,
    const float* __restrict__ l1W, const float* __restrict__ l1b,
    const float* __restrict__ l2W, const float* __restrict__ l2b,
    float* __restrict__ G, float* __restrict__ SS, float* __restrict__ SS2)
{
    __shared__ float tile[32][33];
    __shared__ float se[256];
    int id = blockIdx.x;
    if (id < 64) {
        int idx = id * 256 + threadIdx.x;   // 0..16383
        int s = idx >> 4, j = idx & 15;
        float inv0 = exp2f(-(float)j        * (13.287712379549449f / 32.f));
        float inv1 = exp2f(-(float)(16 + j) * (13.287712379549449f / 32.f));
        float sn0, c0, sn1, c1;
        sincosf((float)s * inv0, &sn0, &c0);
        sincosf((float)s * inv1, &sn1, &c1);
        tab[idx] = make_float4(c0, sn0, c1, sn1);
        return;
    }
    if (id < 16448) {
        id -= 64;
        const float* W; bf16* T; int K, N, bx, by;
        if (id < 3072)       { W = W0; T = T0; K = 1024; N = 3072; bx = id % 96;  by = id / 96; }
        else if (id < 4096)  { id -= 3072;  W = W1; T = T1; K = 1024; N = 1024; bx = id & 31;  by = id >> 5; }
        else if (id < 12288) { id -= 4096;  W = W2; T = T2; K = 1024; N = 8192; bx = id & 255; by = id >> 8; }
        else                 { id -= 12288; W = W3; T = T3; K = 4096; N = 1024; bx = id & 31;  by = id >> 5; }
        int n0 = bx * 32, k0 = by * 32;
        int tx = threadIdx.x & 31, ty = threadIdx.x >> 5;
        #pragma unroll
        for (int r = ty; r < 32; r += 8)
            tile[r][tx] = W[(long)(k0 + r) * N + n0 + tx];
        __syncthreads();
        #pragma unroll
        for (int r = ty; r < 32; r += 8)
            T[(long)(n0 + r) * K + k0 + tx] = __float2bfloat16(tile[tx][r]);
        return;
    }
    id -= 16448;
    int bx = id % 24, b = (id / 24) & 3, k0 = (id / 96) * 256;
    if (threadIdx.x < 256) se[threadIdx.x] = emb[b * 1024 + k0 + threadIdx.x];
    __syncthreads();
    int j = bx * 256 + threadIdx.x;   // 0..6143
    int which = j >> 11, col = j & 2047;
    const float* W  = which == 0 ? gW : (which == 1 ? l1W : l2W);
    const float* bb = which == 0 ? gb : (which == 1 ? l1b : l2b);
    float acc = (k0 == 0) ? bb[col] : 0.f;
    #pragma unroll 4
    for (int k = 0; k < 256; ++k) acc += se[k] * W[(long)(k0 + k) * 2048 + col];
    float* out = which == 0 ? G : (which == 1 ? SS : SS2);
    atomicAdd(&out[b * 2048 + col], acc);
}

// ---------------- rms_norm(x,w)*(1+ss[:D]) + ss[D:] -> bf16 ----------------
__global__ __launch_bounds__(256) void rmsmod_kernel(
    const float* __restrict__ x, const float* __restrict__ w,
    const float* __restrict__ ss, bf16* __restrict__ out)
{
    int row = blockIdx.x;        // 0..4095  (b*S + s)
    int b = row >> 10;
    const float* xr = x + (long)row * D_;
    float4 v = ((const float4*)xr)[threadIdx.x];
    float ssum = v.x * v.x + v.y * v.y + v.z * v.z + v.w * v.w;
    #pragma unroll
    for (int off = 32; off; off >>= 1) ssum += __shfl_xor(ssum, off);
    __shared__ float red[4];
    if ((threadIdx.x & 63) == 0) red[threadIdx.x >> 6] = ssum;
    __syncthreads();
    float tot = red[0] + red[1] + red[2] + red[3];
    float n = sqrtf(tot) * (1.f / 32.f);    // / sqrt(1024)
    float inv = 1.f / (n + 1e-6f);
    int d0 = threadIdx.x * 4;
    const float* ssb = ss + b * 2048;
    bf16 t[4];
    t[0] = __float2bfloat16(v.x * inv * w[d0 + 0] * (1.f + ssb[d0 + 0]) + ssb[D_ + d0 + 0]);
    t[1] = __float2bfloat16(v.y * inv * w[d0 + 1] * (1.f + ssb[d0 + 1]) + ssb[D_ + d0 + 1]);
    t[2] = __float2bfloat16(v.z * inv * w[d0 + 2] * (1.f + ssb[d0 + 2]) + ssb[D_ + d0 + 2]);
    t[3] = __float2bfloat16(v.w * inv * w[d0 + 3] * (1.f + ssb[d0 + 3]) + ssb[D_ + d0 + 3]);
    *(uint2*)&out[(long)row * D_ + d0] = *(uint2*)t;
}

// ------ QKV 256x256 engine with fused bias + rope + head-RMS + layout --------
// Wave (wr,wc) owns rows [m0+wr*128,+128) x cols [n0+wc*64,+64) = one head's
// 64 dims. Rope pair (d,d+32) = frags (n,n+2), same lane. Row-RMS = 16-lane
// shfl_xor tree. Trig from ropetab (R13). Q/K stores via per-wave LDS bounce
// (R16): swizzled b16 writes -> packed uint4 reads -> 16B coalesced stores.
__global__ __launch_bounds__(512) void qkvgemm_kernel(
    const bf16* __restrict__ A, const bf16* __restrict__ Bt,
    const float* __restrict__ bias,
    const float* __restrict__ nq_w, const float* __restrict__ nk_w,
    const float4* __restrict__ ropetab,
    bf16* __restrict__ qh, bf16* __restrict__ kh, bf16* __restrict__ vt,
    int N, int K)
{
    __shared__ bf16 sA[2][16384];
    __shared__ bf16 sB[2][16384];
    GEMM256_PROLOG(N >> 8, 256)

    long gAoff[4], gBoff[4];
    #pragma unroll
    for (int q = 0; q < 4; ++q) {
        int c = tid + q * 512;
        int cs = c ^ ((c >> 3) & 7);             // inverse of ((row&7)<<4) byte-XOR
        int row = cs >> 3, col = (cs & 7) * 8;
        gAoff[q] = (long)(m0 + row) * K + col;
        gBoff[q] = (long)(n0 + row) * K + col;
    }

    #pragma unroll
    for (int q = 0; q < 4; ++q) { STG_A(q, 0, 0); STG_B(q, 0, 0); }
    #pragma unroll
    for (int q = 0; q < 4; ++q) { STG_A(q, 1, 64); STG_B(q, 1, 64); }

    f32x4 acc[8][4] = {};
    const int swz = (cl & 7) << 4;               // lane-constant bank swizzle
    const int aRow = (wr * 128 + cl) * 128;
    const int bRow = (wc * 64 + cl) * 128;
    const int cs0 = (qd * 16) ^ swz;
    const int cs1 = (qd * 16 + 64) ^ swz;

    asm volatile("s_waitcnt vmcnt(8)" ::: "memory");
    __builtin_amdgcn_s_barrier();

    GEMM256_LOOP

    // ---- fused epilogue ----
    const int third = n0 >> 10;                  // 0=Q, 1=K, 2=V
    const int h = ((n0 & 1023) >> 6) + wc;       // head
    const int b = m0 >> 10;
    const int s0 = (m0 & 1023) + wr * 128;
    const int colb = n0 + wc * 64;
    float bs0 = bias[colb + cl],      bs1 = bias[colb + 16 + cl];
    float bs2 = bias[colb + 32 + cl], bs3 = bias[colb + 48 + cl];

    if (third == 2) {
        // V: bias + transpose-free packed stores: vt[(b*16+h)*64+d][s]
        #pragma unroll
        for (int n = 0; n < 4; ++n) {
            int d = n * 16 + cl;
            float bs = bias[colb + n * 16 + cl];
            long rowd = ((long)(b * 16 + h) * 64 + d) * 1024;
            #pragma unroll
            for (int m = 0; m < 8; ++m) {
                int sb = s0 + m * 16 + qd * 4;
                bf16 t4[4];
                #pragma unroll
                for (int i = 0; i < 4; ++i)
                    t4[i] = __float2bfloat16(acc[m][n][i] + bs);
                *(uint2*)&vt[rowd + sb] = *(uint2*)t4;
            }
        }
    } else {
        const float* w = (third == 0) ? nq_w : nk_w;
        bf16* dst = (third == 0) ? qh : kh;
        float w0 = w[cl], w1 = w[16 + cl], w2 = w[32 + cl], w3 = w[48 + cl];
        long hb = ((long)(b * 16 + h) * 1024) * 64;
        // wave-private 2KB bounce region in the (dead) sA[0] buffer.
        // Safe: last K-tile (t=15, pb=1) read sA[1]; sA[0] reads retired at
        // t=14's end barrier. Each wave touches only its own 2KB.
        char* wlds = (char*)&sA[0][wave * 1024];
        #pragma unroll
        for (int m = 0; m < 8; ++m) {
            #pragma unroll
            for (int i = 0; i < 4; ++i) {
                int s = s0 + m * 16 + qd * 4 + i;
                float v0 = acc[m][0][i] + bs0, v1 = acc[m][1][i] + bs1;
                float v2 = acc[m][2][i] + bs2, v3 = acc[m][3][i] + bs3;
                float4 cs = ropetab[s * 16 + cl];   // (cos0,sin0,cos1,sin1)
                float r0 = v0 * cs.x - v2 * cs.y;
                float r1 = v1 * cs.z - v3 * cs.w;
                float r2 = v2 * cs.x + v0 * cs.y;
                float r3 = v3 * cs.z + v1 * cs.w;
                float ssq = r0 * r0 + r1 * r1 + r2 * r2 + r3 * r3;
                ssq += __shfl_xor(ssq, 1);
                ssq += __shfl_xor(ssq, 2);
                ssq += __shfl_xor(ssq, 4);
                ssq += __shfl_xor(ssq, 8);
                float innv = 1.f / (sqrtf(ssq) * 0.125f + 1e-6f);   // /sqrt(64)
                int row = qd * 4 + i;
                int xorv = (row & 7) << 4;
                char* wb = wlds + row * 128;
                *(bf16*)(wb + ((cl * 2 +  0) ^ xorv)) = __float2bfloat16(r0 * innv * w0);
                *(bf16*)(wb + ((cl * 2 + 32) ^ xorv)) = __float2bfloat16(r1 * innv * w1);
                *(bf16*)(wb + ((cl * 2 + 64) ^ xorv)) = __float2bfloat16(r2 * innv * w2);
                *(bf16*)(wb + ((cl * 2 + 96) ^ xorv)) = __float2bfloat16(r3 * innv * w3);
            }
            asm volatile("s_waitcnt lgkmcnt(0)" ::: "memory");  // wave-internal RAW
            int rrow = lane >> 2;
            int rx = (rrow & 7) << 4;
            long ro = hb + (long)(s0 + m * 16 + rrow) * 64 + (lane & 3) * 16;
            uint4 u0 = *(const uint4*)(wlds + rrow * 128 + ((((lane & 3) * 32) +  0) ^ rx));
            uint4 u1 = *(const uint4*)(wlds + rrow * 128 + ((((lane & 3) * 32) + 16) ^ rx));
            *(uint4*)&dst[ro]     = u0;
            *(uint4*)&dst[ro + 8] = u1;
        }
    }
}

// -------- fused MLP 256-engine: h = A @ Wt^T + b; ACT = h1 * silu(h2) --------
__global__ __launch_bounds__(512) void gemm256_mlp_kernel(
    const bf16* __restrict__ A, const bf16* __restrict__ Bt,
    const float* __restrict__ bias, bf16* __restrict__ ACT, int K)
{
    __shared__ bf16 sA[2][16384];
    __shared__ bf16 sB[2][16384];
    GEMM256_PROLOG(32, 128)

    long gAoff[4], gBoff[4];
    #pragma unroll
    for (int q = 0; q < 4; ++q) {
        int c = tid + q * 512;
        int cs = c ^ ((c >> 3) & 7);
        int row = cs >> 3, col = (cs & 7) * 8;
        gAoff[q] = (long)(m0 + row) * K + col;
        int pp = row >> 5, hf = (row >> 4) & 1, wi = row & 15;
        gBoff[q] = (long)(hf * 4096 + n0 + pp * 16 + wi) * K + col;
    }

    #pragma unroll
    for (int q = 0; q < 4; ++q) { STG_A(q, 0, 0); STG_B(q, 0, 0); }
    #pragma unroll
    for (int q = 0; q < 4; ++q) { STG_A(q, 1, 64); STG_B(q, 1, 64); }

    f32x4 acc[8][4] = {};
    const int swz = (cl & 7) << 4;
    const int aRow = (wr * 128 + cl) * 128;
    const int bRow = (wc * 64 + cl) * 128;
    const int cs0 = (qd * 16) ^ swz;
    const int cs1 = (qd * 16 + 64) ^ swz;

    asm volatile("s_waitcnt vmcnt(8)" ::: "memory");
    __builtin_amdgcn_s_barrier();

    GEMM256_LOOP

    #pragma unroll
    for (int m = 0; m < 8; ++m) {
        #pragma unroll
        for (int pr = 0; pr < 2; ++pr) {
            int col = n0 + wc * 32 + pr * 16 + cl;
            float bs1 = bias[col];
            float bs2 = bias[4096 + col];
            #pragma unroll
            for (int i = 0; i < 4; ++i) {
                int row = m0 + wr * 128 + m * 16 + qd * 4 + i;
                float h1 = acc[m][pr * 2 + 0][i] + bs1;
                float h2 = acc[m][pr * 2 + 1][i] + bs2;
                float sg = 1.f / (1.f + __expf(-h2));
                ACT[(long)row * 4096 + col] = __float2bfloat16(h1 * h2 * sg);
            }
        }
    }
}

// ------- 256x128 / BK=64 split-K=2 engine (out-proj: N=1024, K=4096) ---------
#define MFMA_HQ(MH)                                                                       \
    __builtin_amdgcn_s_setprio(1);                                                        \
    _Pragma("unroll")                                                                     \
    for (int m = 0; m < 4; ++m) {                                                         \
        _Pragma("unroll")                                                                 \
        for (int n = 0; n < 2; ++n) {                                                     \
            acc[(MH)*4+m][n] = __builtin_amdgcn_mfma_f32_16x16x32_bf16(                   \
                aF[m][0], bF[n][0], acc[(MH)*4+m][n], 0, 0, 0);                           \
            acc[(MH)*4+m][n] = __builtin_amdgcn_mfma_f32_16x16x32_bf16(                   \
                aF[m][1], bF[n][1], acc[(MH)*4+m][n], 0, 0, 0);                           \
        }                                                                                 \
    }                                                                                     \
    __builtin_amdgcn_s_setprio(0);

__global__ __launch_bounds__(512) void gemm256x128_kernel(
    const bf16* __restrict__ A, const bf16* __restrict__ Bt,
    float* __restrict__ P0, float* __restrict__ P1, int N, int K)
{
    __shared__ bf16 sA[2][16384];
    __shared__ bf16 sB[2][8192];
    const int tid = threadIdx.x;
    const int wave = tid >> 6, lane = tid & 63;
    const int wr = wave >> 2, wc = wave & 3;
    const int cl = lane & 15, qd = lane >> 4;

    const int cpx = gridDim.x >> 3;                 // 256 blocks: %8==0 bijective
    int wg = (blockIdx.x & 7) * cpx + (blockIdx.x >> 3);
    const int split = wg >> 7;                      // K-half
    const int w2 = wg & 127;                        // 16 m-tiles x 8 n-tiles
    const int group_id = w2 >> 6;
    const int pid_in = w2 & 63;
    const int m0 = (group_id * 8 + (pid_in & 7)) * 256;
    const int n0 = (pid_in >> 3) * 128;
    const int Kh = K >> 1;
    A  += (long)split * Kh;
    Bt += (long)split * Kh;

    long gAoff[4], gBoff[2];
    #pragma unroll
    for (int q = 0; q < 4; ++q) {
        int c = tid + q * 512;
        int cs = c ^ ((c >> 3) & 7);
        int row = cs >> 3, col = (cs & 7) * 8;
        gAoff[q] = (long)(m0 + row) * K + col;
        if (q < 2) gBoff[q] = (long)(n0 + row) * K + col;
    }

    const int nt = Kh >> 6;
    // prologue: X+B(0), Y(0), X+B(1)
    STG_A(0, 0, 0); STG_A(2, 0, 0); STG_B(0, 0, 0); STG_B(1, 0, 0);
    STG_A(1, 0, 0); STG_A(3, 0, 0);
    if (nt > 1) { STG_A(0, 1, 64); STG_A(2, 1, 64); STG_B(0, 1, 64); STG_B(1, 1, 64); }

    f32x4 acc[8][2] = {};
    const int swz = (cl & 7) << 4;
    const int aRow = (wr * 128 + cl) * 128;
    const int bRow = (wc * 32 + cl) * 128;
    const int cs0 = (qd * 16) ^ swz;
    const int cs1 = (qd * 16 + 64) ^ swz;

    if (nt > 1) { asm volatile("s_waitcnt vmcnt(4)" ::: "memory"); }
    else        { asm volatile("s_waitcnt vmcnt(0)" ::: "memory"); }
    __builtin_amdgcn_s_barrier();

    for (int t = 0; t < nt; ++t) {
        const int pb = t & 1;
        const char* cA = (const char*)sA[pb];
        const char* cB = (const char*)sB[pb];
        bf16x8 aF[4][2], bF[2][2];
        // P1: read A-mh0 (8) + B (4); stage Y(t+1) -> buf[pb^1]
        #pragma unroll
        for (int m = 0; m < 4; ++m) {
            aF[m][0] = *(const bf16x8*)(cA + aRow + m * 2048 + cs0);
            aF[m][1] = *(const bf16x8*)(cA + aRow + m * 2048 + cs1);
        }
        #pragma unroll
        for (int n = 0; n < 2; ++n) {
            bF[n][0] = *(const bf16x8*)(cB + bRow + n * 2048 + cs0);
            bF[n][1] = *(const bf16x8*)(cB + bRow + n * 2048 + cs1);
        }
        if (t + 1 < nt) { STG_A(1, pb ^ 1, (t + 1) << 6); STG_A(3, pb ^ 1, (t + 1) << 6); }
        __builtin_amdgcn_s_barrier();
        asm volatile("s_waitcnt lgkmcnt(0)" ::: "memory");
        MFMA_HQ(0)
        __builtin_amdgcn_s_barrier();
        // P2: read A-mh1 (8); stage X+B(t+2) -> buf[pb]
        #pragma unroll
        for (int m = 0; m < 4; ++m) {
            aF[m][0] = *(const bf16x8*)(cA + aRow + 8192 + m * 2048 + cs0);
            aF[m][1] = *(const bf16x8*)(cA + aRow + 8192 + m * 2048 + cs1);
        }
        if (t + 2 < nt) { STG_A(0, pb, (t + 2) << 6); STG_A(2, pb, (t + 2) << 6);
                          STG_B(0, pb, (t + 2) << 6); STG_B(1, pb, (t + 2) << 6); }
        __builtin_amdgcn_s_barrier();
        asm volatile("s_waitcnt lgkmcnt(0)" ::: "memory");
        MFMA_HQ(1)
        if (t + 2 < nt)      { asm volatile("s_waitcnt vmcnt(4)" ::: "memory"); }
        else if (t + 1 < nt) { asm volatile("s_waitcnt vmcnt(0)" ::: "memory"); }
        __builtin_amdgcn_s_barrier();
    }

    float* P = split ? P1 : P0;
    #pragma unroll
    for (int m = 0; m < 8; ++m) {
        #pragma unroll
        for (int n = 0; n < 2; ++n) {
            int col = n0 + wc * 32 + n * 16 + cl;
            #pragma unroll
            for (int i = 0; i < 4; ++i) {
                int row = m0 + wr * 128 + m * 16 + qd * 4 + i;
                P[(long)row * N + col] = acc[m][n][i];
            }
        }
    }
}

// ------- fuse: out = X1 + gate_mlp * (p0 + p1 + bias)  (float4) --------------
__global__ __launch_bounds__(256) void fuseout_kernel(
    const float* __restrict__ p0, const float* __restrict__ p1,
    const float* __restrict__ bias, const float* __restrict__ resid,
    const float* __restrict__ gates, float* __restrict__ out)
{
    int idx = blockIdx.x * 256 + threadIdx.x;     // over 4096*1024/4
    int row = idx >> 8;
    int b = row >> 10;
    int c4 = (idx & 255) * 4;
    float4 a = ((const float4*)p0)[idx];
    float4 c = ((const float4*)p1)[idx];
    float4 r = ((const float4*)resid)[idx];
    float4 bb = *(const float4*)&bias[c4];
    float4 gg = *(const float4*)&gates[b * 2048 + 1024 + c4];
    float4 o;
    o.x = r.x + gg.x * (a.x + c.x + bb.x);
    o.y = r.y + gg.y * (a.y + c.y + bb.y);
    o.z = r.z + gg.z * (a.z + c.z + bb.z);
    o.w = r.w + gg.w * (a.w + c.w + bb.w);
    ((float4*)out)[idx] = o;
}

// ---------------- 64x64-tile bf16 MFMA GEMM (proj; R5-proven best) -----------
__global__ __launch_bounds__(256) void gemm64_kernel(
    const bf16* __restrict__ A, const bf16* __restrict__ Bt,
    const float* __restrict__ bias,
    bf16* __restrict__ Cb, float* __restrict__ Cf,
    const float* __restrict__ resid, const float* __restrict__ gates, int gate_off,
    int Mrows, int N, int K, int mode)
{
    __shared__ bf16 sA[64 * 32];
    __shared__ bf16 sB[64 * 32];
    const int tid = threadIdx.x;
    const int wave = tid >> 6, lane = tid & 63;
    const int num_pid_n = N >> 6;
    const int pid = blockIdx.x;
    const int group_size = 8 * num_pid_n;
    const int group_id = pid / group_size;
    const int pid_in = pid - group_id * group_size;
    const int pid_m = group_id * 8 + (pid_in & 7);
    const int pid_n = pid_in >> 3;
    const int m0 = pid_m * 64, n0 = pid_n * 64;
    const int wm = (wave & 1) * 32, wn = (wave >> 1) * 32;
    const int cl = lane & 15, qd = lane >> 4;

    f32x4 acc[2][2] = {};

    const int c = tid;
    const int rr = c >> 2, ss = (c & 3) ^ ((c >> 3) & 3);
    const bf16* gA = A + (long)(m0 + rr) * K + ss * 8;
    const bf16* gB = Bt + (long)(n0 + rr) * K + ss * 8;
    bf16* lA = &sA[wave * 512];
    bf16* lB = &sB[wave * 512];

    const int q8s = (qd ^ ((cl >> 1) & 3)) * 8;

    for (int kc = 0; kc < K; kc += 32) {
        gl_lds16(gA + kc, lA);
        gl_lds16(gB + kc, lB);
        __syncthreads();
        bf16x8 af[2], bfr[2];
        #pragma unroll
        for (int t = 0; t < 2; ++t)
            af[t] = *(const bf16x8*)&sA[(wm + cl + t * 16) * 32 + q8s];
        #pragma unroll
        for (int u = 0; u < 2; ++u)
            bfr[u] = *(const bf16x8*)&sB[(wn + cl + u * 16) * 32 + q8s];
        #pragma unroll
        for (int t = 0; t < 2; ++t)
            #pragma unroll
            for (int u = 0; u < 2; ++u)
                acc[t][u] = __builtin_amdgcn_mfma_f32_16x16x32_bf16(af[t], bfr[u], acc[t][u], 0, 0, 0);
        __syncthreads();
    }

    #pragma unroll
    for (int t = 0; t < 2; ++t) {
        #pragma unroll
        for (int u = 0; u < 2; ++u) {
            int col = n0 + wn + u * 16 + cl;
            float bs = bias[col];
            #pragma unroll
            for (int i = 0; i < 4; ++i) {
                int row = m0 + wm + t * 16 + qd * 4 + i;
                float v = acc[t][u][i] + bs;
                if (mode == 0) {
                    Cb[(long)row * N + col] = __float2bfloat16(v);
                } else {
                    int b = row >> 10;
                    float g = gates[b * 2048 + gate_off + col];
                    Cf[(long)row * N + col] = resid[(long)row * N + col] + g * v;
                }
            }
        }
    }
}

// ---------------- fused flash-style attention, fixed-shift softmax ------------
// Q,K rows are RMS-normalized (unit weights) -> scores in [-8,8]; fixed shift 8.
// R14: linear [64][128B] LDS tiles + XOR swizzle, gl_lds w/ pre-swizzled src.
// R15: double-buffered K/V + counted vmcnt(4).
// R16: Q in REGISTERS (2 b128/lane) -> LDS 48->40KB -> 4 blocks/CU (one fully
// resident 1024-block pass); s_setprio(1) around MFMA clusters (T5, m191).
__global__ __launch_bounds__(256) void attn_kernel(
    const bf16* __restrict__ qh, const bf16* __restrict__ kh, const bf16* __restrict__ vt,
    bf16* __restrict__ ao)
{
    const int bh = blockIdx.y;
    const int q0 = blockIdx.x * 64;
    const int tid = threadIdx.x, wave = tid >> 6, lane = tid & 63;
    const int cl = lane & 15, qd = lane >> 4;

    __shared__ bf16 sK[2][64 * 64];
    __shared__ bf16 sV[2][64 * 64];
    __shared__ bf16 sP[4][16 * 64];

    // staging geometry: thread a -> row = a>>3, source chunk = (a&7)^(row&7)
    const int r0 = tid >> 3;
    const int c0 = (tid & 7) ^ (r0 & 7);
    const int r1 = (tid + 256) >> 3;
    const int c1 = ((tid + 256) & 7) ^ (r1 & 7);

    const bf16* Kg = kh + (long)bh * S_ * 64;
    const bf16* Vg = vt + (long)bh * 64 * S_;

    #define ATTN_STAGE(t) {                                                          \
        int kv = (t) * 64;                                                           \
        gl_lds16(Kg + (long)(kv + r0) * 64 + c0 * 8, &sK[(t) & 1][(long)tid * 8]);   \
        gl_lds16(Kg + (long)(kv + r1) * 64 + c1 * 8, &sK[(t) & 1][(long)(tid + 256) * 8]); \
        gl_lds16(Vg + (long)r0 * S_ + kv + c0 * 8, &sV[(t) & 1][(long)tid * 8]);     \
        gl_lds16(Vg + (long)r1 * S_ + kv + c1 * 8, &sV[(t) & 1][(long)(tid + 256) * 8]); }

    // prologue: Q fragment to registers (issued first), then K/V tile 0
    bf16x8 qf[2];
    {
        const bf16* Qg = qh + (long)bh * S_ * 64 + (long)q0 * 64;
        qf[0] = *(const bf16x8*)&Qg[(wave * 16 + cl) * 64 + qd * 8];
        qf[1] = *(const bf16x8*)&Qg[(wave * 16 + cl) * 64 + 32 + qd * 8];
        ATTN_STAGE(0)
    }

    float l_i[4] = {0.f, 0.f, 0.f, 0.f};
    f32x4 o_acc[4] = {};

    const int swz = (cl & 7) << 4;               // lane-constant read XOR
    char* cP = (char*)sP[wave];

    for (int t = 0; t < 16; ++t) {
        __builtin_amdgcn_s_barrier();            // all waves done reading buf[(t+1)&1]
        if (t + 1 < 16) {
            ATTN_STAGE(t + 1)                    // 4 loads in flight across compute(t)
            asm volatile("s_waitcnt vmcnt(4)" ::: "memory");   // tile t (and qf) landed
        } else {
            asm volatile("s_waitcnt vmcnt(0)" ::: "memory");
        }
        __builtin_amdgcn_s_barrier();            // tile t visible to all waves
        const char* cK = (const char*)sK[t & 1];
        const char* cV = (const char*)sV[t & 1];

        // S = Q_wave (16 x 64) @ K_tile^T  -> 4 col-tiles of 16
        f32x4 sfr[4] = {};
        __builtin_amdgcn_s_setprio(1);
        #pragma unroll
        for (int ks = 0; ks < 2; ++ks) {
            const int co = (ks * 64 + qd * 16) ^ swz;
            #pragma unroll
            for (int u = 0; u < 4; ++u) {
                bf16x8 bk = *(const bf16x8*)(cK + (u * 16 + cl) * 128 + co);
                sfr[u] = __builtin_amdgcn_mfma_f32_16x16x32_bf16(qf[ks], bk, sfr[u], 0, 0, 0);
            }
        }
        __builtin_amdgcn_s_setprio(0);

        // fixed-shift softmax: p = exp(s*0.125 - 8), accumulate l_i
        #pragma unroll
        for (int i = 0; i < 4; ++i) {
            int rowp = qd * 4 + i;
            char* pb = cP + rowp * 128;
            const int xorv = (rowp & 7) << 4;
            float sum = 0.f;
            #pragma unroll
            for (int u = 0; u < 4; ++u) {
                float p = __expf(sfr[u][i] * 0.125f - 8.f);
                sum += p;
                *(bf16*)(pb + ((u * 32 + cl * 2) ^ xorv)) = __float2bfloat16(p);
            }
            sum += __shfl_xor(sum, 1);
            sum += __shfl_xor(sum, 2);
            sum += __shfl_xor(sum, 4);
            sum += __shfl_xor(sum, 8);
            l_i[i] += sum;
        }

        // O += P (16 x 64kv) @ V (64kv x 64d); P read back in A-layout from LDS
        __builtin_amdgcn_s_setprio(1);
        #pragma unroll
        for (int ks = 0; ks < 2; ++ks) {
            const int co = (ks * 64 + qd * 16) ^ swz;
            bf16x8 ap = *(const bf16x8*)(cP + cl * 128 + co);
            #pragma unroll
            for (int u = 0; u < 4; ++u) {
                bf16x8 bv = *(const bf16x8*)(cV + (u * 16 + cl) * 128 + co);
                o_acc[u] = __builtin_amdgcn_mfma_f32_16x16x32_bf16(ap, bv, o_acc[u], 0, 0, 0);
            }
        }
        __builtin_amdgcn_s_setprio(0);
    }
    #undef ATTN_STAGE

    // epilogue: ao[b, s, h*64+d]
    #pragma unroll
    for (int i = 0; i < 4; ++i) {
        float invl = 1.f / l_i[i];
        int row = q0 + wave * 16 + qd * 4 + i;
        #pragma unroll
        for (int u = 0; u < 4; ++u) {
            int d = u * 16 + cl;
            ao[((long)(bh >> 4) * S_ + row) * D_ + (bh & 15) * 64 + d] =
                __float2bfloat16(o_acc[u][i] * invl);
        }
    }
}

extern "C" void kernel_launch(void* const* d_in, const int* in_sizes, int n_in,
                              void* d_out, int out_size, void* d_ws, size_t ws_size,
                              hipStream_t stream) {
    const float* x       = (const float*)d_in[0];
    const float* emb     = (const float*)d_in[1];
    const float* ln1_w   = (const float*)d_in[2];
    const float* ln1_lW  = (const float*)d_in[3];
    const float* ln1_lb  = (const float*)d_in[4];
    const float* ln2_w   = (const float*)d_in[5];
    const float* ln2_lW  = (const float*)d_in[6];
    const float* ln2_lb  = (const float*)d_in[7];
    const float* qkv_W   = (const float*)d_in[8];
    const float* qkv_b   = (const float*)d_in[9];
    const float* proj_W  = (const float*)d_in[10];
    const float* proj_b  = (const float*)d_in[11];
    const float* nq_w    = (const float*)d_in[12];
    const float* nk_w    = (const float*)d_in[13];
    const float* mlp_W   = (const float*)d_in[14];
    const float* mlp_b   = (const float*)d_in[15];
    const float* out_W   = (const float*)d_in[16];
    const float* out_b   = (const float*)d_in[17];
    const float* gates_W = (const float*)d_in[18];
    const float* gates_b = (const float*)d_in[19];
    float* out = (float*)d_out;

    // workspace layout (all offsets 256B aligned)
    char* p = (char*)d_ws;
    if (ws_size < 159481856UL) return;  // loud failure rather than OOB corruption
    bf16* WT_QKV  = (bf16*)p;  p += 6291456;   // [3072][1024]
    bf16* WT_PROJ = (bf16*)p;  p += 2097152;   // [1024][1024]
    bf16* WT_MLP  = (bf16*)p;  p += 16777216;  // [8192][1024]
    bf16* WT_OUT  = (bf16*)p;  p += 8388608;   // [1024][4096]
    float* G      = (float*)p; p += 32768;     // [4][2048]
    float* SSb    = (float*)p; p += 32768;
    float* SS2b   = (float*)p; p += 32768;
    float* X1     = (float*)p; p += 16777216;  // f32 [4096][1024]
    bf16* XN2     = (bf16*)p;  p += 8388608;
    bf16* ACT     = (bf16*)p;  p += 33554432;  // [4096][4096]
    char* REG = p;                              // reused region
    bf16* XN   = (bf16*)(REG);
    bf16* QH   = (bf16*)(REG + 33554432);      // [B,H,S,HD]
    bf16* KH   = (bf16*)(REG + 41943040);
    bf16* VT   = (bf16*)(REG + 50331648);      // [B,H,HD,S]
    bf16* AO   = (bf16*)(REG + 58720256);      // [4096][1024]
    // split-K partials for the out-proj: reuse REG head (XN dead by then)
    float* PF0 = (float*)(REG);                // [4096][1024] f32
    float* PF1 = (float*)(REG + 16777216);
    // rope table: head of X1 (X1 is written only later by the proj GEMM)
    float4* ROPETAB = (float4*)X1;             // [1024][16] float4 = 256 KB

    dim3 blk(256);
    // zero G/SSb/SS2b (96 KB) for embgemm's atomicAdd k-split
    hipMemsetAsync(G, 0, 98304, stream);
    // merged prep: ropetab (64) + transposes (16384) + embgemm (384)
    prep_kernel<<<dim3(16832), blk, 0, stream>>>(ROPETAB,
                                                 qkv_W, WT_QKV, proj_W, WT_PROJ,
                                                 mlp_W, WT_MLP, out_W, WT_OUT,
                                                 emb, gates_W, gates_b, ln1_lW, ln1_lb,
                                                 ln2_lW, ln2_lb, G, SSb, SS2b);
    rmsmod_kernel<<<dim3(4096), blk, 0, stream>>>(x, ln1_w, SSb, XN);
    // QKV GEMM + fused bias/rope/head-norm/layout: M=4096 N=3072 K=1024
    qkvgemm_kernel<<<dim3(192), dim3(512), 0, stream>>>(XN, WT_QKV, qkv_b, nq_w, nk_w,
                                                        ROPETAB, QH, KH, VT, 3072, 1024);
    attn_kernel<<<dim3(16, 64), blk, 0, stream>>>(QH, KH, VT, AO);
    gemm64_kernel<<<dim3(1024), blk, 0, stream>>>(AO, WT_PROJ, proj_b, nullptr, X1,
                                                  x, G, 0, 4096, 1024, 1024, 1);
    rmsmod_kernel<<<dim3(4096), blk, 0, stream>>>(X1, ln2_w, SS2b, XN2);
    // fused MLP: 16 m-tiles x 32 fused col-tiles = 512 blocks
    gemm256_mlp_kernel<<<dim3(512), dim3(512), 0, stream>>>(XN2, WT_MLP, mlp_b, ACT, 1024);
    // out-proj: 256x128 split-K=2 engine (256 blocks = exact CU fill) + fuse
    gemm256x128_kernel<<<dim3(256), dim3(512), 0, stream>>>(ACT, WT_OUT, PF0, PF1, 1024, 4096);
    fuseout_kernel<<<dim3(4096), blk, 0, stream>>>(PF0, PF1, out_b, X1, G, out);
}

// Round 9
// 442.200 us; speedup vs baseline: 1.0242x; 1.0178x over previous
//
#include <hip/hip_runtime.h>
#include <hip/hip_bf16.h>
#include <math.h>

#define B_ 4
#define S_ 1024
#define D_ 1024
#define H_ 16
#define HD_ 64
#define M_ 4096
#define E_ 1024

using bf16 = __hip_bfloat16;
typedef short bf16x8 __attribute__((ext_vector_type(8)));
typedef float f32x4 __attribute__((ext_vector_type(4)));

__device__ __forceinline__ void gl_lds16(const void* g, void* l) {
    __builtin_amdgcn_global_load_lds(
        (__attribute__((address_space(1))) void*)(g),
        (__attribute__((address_space(3))) void*)(l), 16, 0, 0);
}

// LDS swizzle (R9, measured): physical = logical ^ ((row&7)<<4) on
// [rows][64 k-elem] bf16 tiles. Source pre-swizzle in 16B-chunk space:
// c ^= (row&7). Fragment-read XOR ((cl&7)<<4) lane-constant, hoisted.

// Engine lessons (R4-R17, measured):
//  - 256x256 8-phase + swizzle + counted vmcnt: 849 TF @ K=1024 == m248 rate.
//  - ERRATA (R16): attn pad-72 was NOT conflicted (uniform b128 floor);
//    attn R14-R16 changes summed to only ~7us. Attn ~at its structure's rate.
//  - R17: prep_kernel surfaced at 79.8us / 12.6% HBM -- 6x above roofline.
//    Scalar 2B bf16 transpose stores + 4x re-read of emb W panels (G13).
//    Now: float4 loads + [64][72] bf16 LDS tile + uint4 stores; embgemm
//    one W-panel read for all 4 batches. Target ~28us.
//  - gemm256_mlp is the cross-round clock CONTROL (unchanged since R10).

#define STG_A(q, pb, kc) gl_lds16(A  + gAoff[q] + (kc), &sA[pb][(q) * 4096 + tid * 8])
#define STG_B(q, pb, kc) gl_lds16(Bt + gBoff[q] + (kc), &sB[pb][(q) * 4096 + tid * 8])

#define LDA(mh, m, h) (*(const bf16x8*)(cA + aRow + (mh) * 8192 + (m) * 2048 + (h)))
#define LDB(nh, n, h) (*(const bf16x8*)(cB + bRow + (nh) * 4096 + (n) * 2048 + (h)))

#define MFMA_QUAD(MH, NH, BF)                                                             \
    __builtin_amdgcn_s_setprio(1);                                                        \
    _Pragma("unroll")                                                                     \
    for (int m = 0; m < 4; ++m) {                                                         \
        _Pragma("unroll")                                                                 \
        for (int n = 0; n < 2; ++n) {                                                     \
            acc[(MH)*4+m][(NH)*2+n] = __builtin_amdgcn_mfma_f32_16x16x32_bf16(            \
                aF[m][0], BF[n][0], acc[(MH)*4+m][(NH)*2+n], 0, 0, 0);                    \
            acc[(MH)*4+m][(NH)*2+n] = __builtin_amdgcn_mfma_f32_16x16x32_bf16(            \
                aF[m][1], BF[n][1], acc[(MH)*4+m][(NH)*2+n], 0, 0, 0);                    \
        }                                                                                 \
    }                                                                                     \
    __builtin_amdgcn_s_setprio(0);

// 8-phase K-loop (256x256). Staging WAR-safe by barrier construction.
#define GEMM256_LOOP                                                                      \
    const int nt = K >> 6;                                                                \
    for (int t = 0; t < nt; ++t) {                                                        \
        const int pb = t & 1;                                                             \
        const char* cA = (const char*)sA[pb];                                             \
        const char* cB = (const char*)sB[pb];                                             \
        const int kc2 = (t + 2) << 6;                                                     \
        const bool pf = (t + 2) < nt;                                                     \
        bf16x8 aF[4][2], b0F[2][2], b1F[2][2];                                            \
        /* P1: read A-mh0 (8) + B-nh0 (4); MFMA (0,0) */                                  \
        _Pragma("unroll")                                                                 \
        for (int m = 0; m < 4; ++m) {                                                     \
            aF[m][0] = LDA(0, m, cs0);                                                    \
            aF[m][1] = LDA(0, m, cs1);                                                    \
        }                                                                                 \
        _Pragma("unroll")                                                                 \
        for (int n = 0; n < 2; ++n) {                                                     \
            b0F[n][0] = LDB(0, n, cs0);                                                   \
            b0F[n][1] = LDB(0, n, cs1);                                                   \
        }                                                                                 \
        __builtin_amdgcn_s_barrier();                                                     \
        asm volatile("s_waitcnt lgkmcnt(0)" ::: "memory");                                \
        MFMA_QUAD(0, 0, b0F)                                                              \
        __builtin_amdgcn_s_barrier();                                                     \
        /* P2: read B-nh1 (4); prefetch A units 0,2 of t+2; MFMA (0,1) */                 \
        _Pragma("unroll")                                                                 \
        for (int n = 0; n < 2; ++n) {                                                     \
            b1F[n][0] = LDB(1, n, cs0);                                                   \
            b1F[n][1] = LDB(1, n, cs1);                                                   \
        }                                                                                 \
        if (pf) { STG_A(0, pb, kc2); STG_A(2, pb, kc2); }                                 \
        __builtin_amdgcn_s_barrier();                                                     \
        asm volatile("s_waitcnt lgkmcnt(0)" ::: "memory");                                \
        MFMA_QUAD(0, 1, b1F)                                                              \
        __builtin_amdgcn_s_barrier();                                                     \
        /* P3: read A-mh1 (8); prefetch all B of t+2; MFMA (1,1) */                       \
        _Pragma("unroll")                                                                 \
        for (int m = 0; m < 4; ++m) {                                                     \
            aF[m][0] = LDA(1, m, cs0);                                                    \
            aF[m][1] = LDA(1, m, cs1);                                                    \
        }                                                                                 \
        if (pf) { STG_B(0, pb, kc2); STG_B(1, pb, kc2);                                   \
                  STG_B(2, pb, kc2); STG_B(3, pb, kc2); }                                 \
        __builtin_amdgcn_s_barrier();                                                     \
        asm volatile("s_waitcnt lgkmcnt(0)" ::: "memory");                                \
        MFMA_QUAD(1, 1, b1F)                                                              \
        __builtin_amdgcn_s_barrier();                                                     \
        /* P4: prefetch A units 1,3; MFMA (1,0); counted vmcnt */                         \
        if (pf) { STG_A(1, pb, kc2); STG_A(3, pb, kc2); }                                 \
        __builtin_amdgcn_s_barrier();                                                     \
        asm volatile("s_waitcnt lgkmcnt(0)" ::: "memory");                                \
        MFMA_QUAD(1, 0, b0F)                                                              \
        if (pf)              { asm volatile("s_waitcnt vmcnt(8)" ::: "memory"); }         \
        else if (t + 1 < nt) { asm volatile("s_waitcnt vmcnt(0)" ::: "memory"); }         \
        __builtin_amdgcn_s_barrier();                                                     \
    }

// shared block-index setup for the 256-wide engines
#define GEMM256_PROLOG(NPN, N0MUL)                                                        \
    const int tid = threadIdx.x;                                                          \
    const int wave = tid >> 6, lane = tid & 63;                                           \
    const int wr = wave >> 2, wc = wave & 3;                                              \
    const int cl = lane & 15, qd = lane >> 4;                                             \
    const int num_pid_n = (NPN);                                                          \
    const int cpx = gridDim.x >> 3;                                                       \
    int wg = (blockIdx.x & 7) * cpx + (blockIdx.x >> 3);                                  \
    const int group_size = 8 * num_pid_n;                                                 \
    const int group_id = wg / group_size;                                                 \
    const int pid_in = wg - group_id * group_size;                                        \
    const int m0 = (group_id * 8 + (pid_in & 7)) * 256;                                   \
    const int n0 = (pid_in >> 3) * (N0MUL);

// ---- merged prep: rope table + 4 weight transposes + emb GEMM (1 dispatch) --
// R17: transposes in 64x64 tiles -- float4 loads (16B/lane), bf16 LDS tile
// [64][72] (144B rows, 16B-aligned), uint4 stores (16B/lane). embgemm loads
// each W panel ONCE and accumulates all 4 batches (se[4][256]).
// Block ranges: [0,64) ropetab | [64,4160) transposes | [4160,4256) embgemm.
__global__ __launch_bounds__(256) void prep_kernel(
    float4* __restrict__ tab,
    const float* __restrict__ W0, bf16* __restrict__ T0,
    const float* __restrict__ W1, bf16* __restrict__ T1,
    const float* __restrict__ W2, bf16* __restrict__ T2,
    const float* __restrict__ W3, bf16* __restrict__ T3,
    const float* __restrict__ emb,
    const float* __restrict__ gW, const float* __restrict__ gb,
    const float* __restrict__ l1W, const float* __restrict__ l1b,
    const float* __restrict__ l2W, const float* __restrict__ l2b,
    float* __restrict__ G, float* __restrict__ SS, float* __restrict__ SS2)
{
    __shared__ bf16 tile[64][72];
    __shared__ float se[4][256];
    const int tid = threadIdx.x;
    int id = blockIdx.x;
    if (id < 64) {
        int idx = id * 256 + tid;   // 0..16383
        int s = idx >> 4, j = idx & 15;
        float inv0 = exp2f(-(float)j        * (13.287712379549449f / 32.f));
        float inv1 = exp2f(-(float)(16 + j) * (13.287712379549449f / 32.f));
        float sn0, c0, sn1, c1;
        sincosf((float)s * inv0, &sn0, &c0);
        sincosf((float)s * inv1, &sn1, &c1);
        tab[idx] = make_float4(c0, sn0, c1, sn1);
        return;
    }
    if (id < 4160) {
        id -= 64;                   // 0..4095: 64x64 transpose tiles
        const float* W; bf16* T; int K, N, bx, by;
        if (id < 768)        {             W = W0; T = T0; K = 1024; N = 3072; bx = id % 48;  by = id / 48; }
        else if (id < 1024)  { id -= 768;  W = W1; T = T1; K = 1024; N = 1024; bx = id & 15;  by = id >> 4; }
        else if (id < 3072)  { id -= 1024; W = W2; T = T2; K = 1024; N = 8192; bx = id & 127; by = id >> 7; }
        else                 { id -= 3072; W = W3; T = T3; K = 4096; N = 1024; bx = id & 15;  by = id >> 4; }
        int n0 = bx * 64, k0 = by * 64;
        // load: float4 along N; write transposed into LDS (scalar b16, padded)
        int tx = tid & 15, ty = tid >> 4;            // 16 cols-of-4 x 16 rows
        #pragma unroll
        for (int r = 0; r < 4; ++r) {
            int k = ty + r * 16;
            float4 v = *(const float4*)&W[(long)(k0 + k) * N + n0 + tx * 4];
            tile[tx * 4 + 0][k] = __float2bfloat16(v.x);
            tile[tx * 4 + 1][k] = __float2bfloat16(v.y);
            tile[tx * 4 + 2][k] = __float2bfloat16(v.z);
            tile[tx * 4 + 3][k] = __float2bfloat16(v.w);
        }
        __syncthreads();
        // store: uint4 along K (16B/lane)
        #pragma unroll
        for (int p = 0; p < 2; ++p) {
            int idx = tid + p * 256;
            int n = idx >> 3, c = idx & 7;
            uint4 u = *(const uint4*)&tile[n][c * 8];
            *(uint4*)&T[(long)(n0 + n) * K + k0 + c * 8] = u;
        }
        return;
    }
    // embgemm: 96 blocks (24 col-groups x 4 k-splits); all 4 batches per block
    id -= 4160;
    int bx = id % 24, k0 = (id / 24) * 256;
    #pragma unroll
    for (int b = 0; b < 4; ++b)
        se[b][tid] = emb[b * 1024 + k0 + tid];
    __syncthreads();
    int j = bx * 256 + tid;   // 0..6143
    int which = j >> 11, col = j & 2047;
    const float* W  = which == 0 ? gW : (which == 1 ? l1W : l2W);
    const float* bb = which == 0 ? gb : (which == 1 ? l1b : l2b);
    float* out = which == 0 ? G : (which == 1 ? SS : SS2);
    float a0 = 0.f, a1 = 0.f, a2 = 0.f, a3 = 0.f;
    if (k0 == 0) { float bv = bb[col]; a0 = bv; a1 = bv; a2 = bv; a3 = bv; }
    #pragma unroll 4
    for (int k = 0; k < 256; ++k) {
        float wv = W[(long)(k0 + k) * 2048 + col];
        a0 += se[0][k] * wv;
        a1 += se[1][k] * wv;
        a2 += se[2][k] * wv;
        a3 += se[3][k] * wv;
    }
    atomicAdd(&out[col], a0);
    atomicAdd(&out[2048 + col], a1);
    atomicAdd(&out[4096 + col], a2);
    atomicAdd(&out[6144 + col], a3);
}

// ---------------- rms_norm(x,w)*(1+ss[:D]) + ss[D:] -> bf16 ----------------
__global__ __launch_bounds__(256) void rmsmod_kernel(
    const float* __restrict__ x, const float* __restrict__ w,
    const float* __restrict__ ss, bf16* __restrict__ out)
{
    int row = blockIdx.x;        // 0..4095  (b*S + s)
    int b = row >> 10;
    const float* xr = x + (long)row * D_;
    float4 v = ((const float4*)xr)[threadIdx.x];
    float ssum = v.x * v.x + v.y * v.y + v.z * v.z + v.w * v.w;
    #pragma unroll
    for (int off = 32; off; off >>= 1) ssum += __shfl_xor(ssum, off);
    __shared__ float red[4];
    if ((threadIdx.x & 63) == 0) red[threadIdx.x >> 6] = ssum;
    __syncthreads();
    float tot = red[0] + red[1] + red[2] + red[3];
    float n = sqrtf(tot) * (1.f / 32.f);    // / sqrt(1024)
    float inv = 1.f / (n + 1e-6f);
    int d0 = threadIdx.x * 4;
    const float* ssb = ss + b * 2048;
    bf16 t[4];
    t[0] = __float2bfloat16(v.x * inv * w[d0 + 0] * (1.f + ssb[d0 + 0]) + ssb[D_ + d0 + 0]);
    t[1] = __float2bfloat16(v.y * inv * w[d0 + 1] * (1.f + ssb[d0 + 1]) + ssb[D_ + d0 + 1]);
    t[2] = __float2bfloat16(v.z * inv * w[d0 + 2] * (1.f + ssb[d0 + 2]) + ssb[D_ + d0 + 2]);
    t[3] = __float2bfloat16(v.w * inv * w[d0 + 3] * (1.f + ssb[d0 + 3]) + ssb[D_ + d0 + 3]);
    *(uint2*)&out[(long)row * D_ + d0] = *(uint2*)t;
}

// ------ QKV 256x256 engine with fused bias + rope + head-RMS + layout --------
__global__ __launch_bounds__(512) void qkvgemm_kernel(
    const bf16* __restrict__ A, const bf16* __restrict__ Bt,
    const float* __restrict__ bias,
    const float* __restrict__ nq_w, const float* __restrict__ nk_w,
    const float4* __restrict__ ropetab,
    bf16* __restrict__ qh, bf16* __restrict__ kh, bf16* __restrict__ vt,
    int N, int K)
{
    __shared__ bf16 sA[2][16384];
    __shared__ bf16 sB[2][16384];
    GEMM256_PROLOG(N >> 8, 256)

    long gAoff[4], gBoff[4];
    #pragma unroll
    for (int q = 0; q < 4; ++q) {
        int c = tid + q * 512;
        int cs = c ^ ((c >> 3) & 7);             // inverse of ((row&7)<<4) byte-XOR
        int row = cs >> 3, col = (cs & 7) * 8;
        gAoff[q] = (long)(m0 + row) * K + col;
        gBoff[q] = (long)(n0 + row) * K + col;
    }

    #pragma unroll
    for (int q = 0; q < 4; ++q) { STG_A(q, 0, 0); STG_B(q, 0, 0); }
    #pragma unroll
    for (int q = 0; q < 4; ++q) { STG_A(q, 1, 64); STG_B(q, 1, 64); }

    f32x4 acc[8][4] = {};
    const int swz = (cl & 7) << 4;               // lane-constant bank swizzle
    const int aRow = (wr * 128 + cl) * 128;
    const int bRow = (wc * 64 + cl) * 128;
    const int cs0 = (qd * 16) ^ swz;
    const int cs1 = (qd * 16 + 64) ^ swz;

    asm volatile("s_waitcnt vmcnt(8)" ::: "memory");
    __builtin_amdgcn_s_barrier();

    GEMM256_LOOP

    // ---- fused epilogue ----
    const int third = n0 >> 10;                  // 0=Q, 1=K, 2=V
    const int h = ((n0 & 1023) >> 6) + wc;       // head
    const int b = m0 >> 10;
    const int s0 = (m0 & 1023) + wr * 128;
    const int colb = n0 + wc * 64;
    float bs0 = bias[colb + cl],      bs1 = bias[colb + 16 + cl];
    float bs2 = bias[colb + 32 + cl], bs3 = bias[colb + 48 + cl];

    if (third == 2) {
        // V: bias + transpose-free packed stores: vt[(b*16+h)*64+d][s]
        #pragma unroll
        for (int n = 0; n < 4; ++n) {
            int d = n * 16 + cl;
            float bs = bias[colb + n * 16 + cl];
            long rowd = ((long)(b * 16 + h) * 64 + d) * 1024;
            #pragma unroll
            for (int m = 0; m < 8; ++m) {
                int sb = s0 + m * 16 + qd * 4;
                bf16 t4[4];
                #pragma unroll
                for (int i = 0; i < 4; ++i)
                    t4[i] = __float2bfloat16(acc[m][n][i] + bs);
                *(uint2*)&vt[rowd + sb] = *(uint2*)t4;
            }
        }
    } else {
        const float* w = (third == 0) ? nq_w : nk_w;
        bf16* dst = (third == 0) ? qh : kh;
        float w0 = w[cl], w1 = w[16 + cl], w2 = w[32 + cl], w3 = w[48 + cl];
        long hb = ((long)(b * 16 + h) * 1024) * 64;
        // wave-private 2KB bounce region in the (dead) sA[0] buffer.
        char* wlds = (char*)&sA[0][wave * 1024];
        #pragma unroll
        for (int m = 0; m < 8; ++m) {
            #pragma unroll
            for (int i = 0; i < 4; ++i) {
                int s = s0 + m * 16 + qd * 4 + i;
                float v0 = acc[m][0][i] + bs0, v1 = acc[m][1][i] + bs1;
                float v2 = acc[m][2][i] + bs2, v3 = acc[m][3][i] + bs3;
                float4 cs = ropetab[s * 16 + cl];   // (cos0,sin0,cos1,sin1)
                float r0 = v0 * cs.x - v2 * cs.y;
                float r1 = v1 * cs.z - v3 * cs.w;
                float r2 = v2 * cs.x + v0 * cs.y;
                float r3 = v3 * cs.z + v1 * cs.w;
                float ssq = r0 * r0 + r1 * r1 + r2 * r2 + r3 * r3;
                ssq += __shfl_xor(ssq, 1);
                ssq += __shfl_xor(ssq, 2);
                ssq += __shfl_xor(ssq, 4);
                ssq += __shfl_xor(ssq, 8);
                float innv = 1.f / (sqrtf(ssq) * 0.125f + 1e-6f);   // /sqrt(64)
                int row = qd * 4 + i;
                int xorv = (row & 7) << 4;
                char* wb = wlds + row * 128;
                *(bf16*)(wb + ((cl * 2 +  0) ^ xorv)) = __float2bfloat16(r0 * innv * w0);
                *(bf16*)(wb + ((cl * 2 + 32) ^ xorv)) = __float2bfloat16(r1 * innv * w1);
                *(bf16*)(wb + ((cl * 2 + 64) ^ xorv)) = __float2bfloat16(r2 * innv * w2);
                *(bf16*)(wb + ((cl * 2 + 96) ^ xorv)) = __float2bfloat16(r3 * innv * w3);
            }
            asm volatile("s_waitcnt lgkmcnt(0)" ::: "memory");  // wave-internal RAW
            int rrow = lane >> 2;
            int rx = (rrow & 7) << 4;
            long ro = hb + (long)(s0 + m * 16 + rrow) * 64 + (lane & 3) * 16;
            uint4 u0 = *(const uint4*)(wlds + rrow * 128 + ((((lane & 3) * 32) +  0) ^ rx));
            uint4 u1 = *(const uint4*)(wlds + rrow * 128 + ((((lane & 3) * 32) + 16) ^ rx));
            *(uint4*)&dst[ro]     = u0;
            *(uint4*)&dst[ro + 8] = u1;
        }
    }
}

// -------- fused MLP 256-engine: h = A @ Wt^T + b; ACT = h1 * silu(h2) --------
__global__ __launch_bounds__(512) void gemm256_mlp_kernel(
    const bf16* __restrict__ A, const bf16* __restrict__ Bt,
    const float* __restrict__ bias, bf16* __restrict__ ACT, int K)
{
    __shared__ bf16 sA[2][16384];
    __shared__ bf16 sB[2][16384];
    GEMM256_PROLOG(32, 128)

    long gAoff[4], gBoff[4];
    #pragma unroll
    for (int q = 0; q < 4; ++q) {
        int c = tid + q * 512;
        int cs = c ^ ((c >> 3) & 7);
        int row = cs >> 3, col = (cs & 7) * 8;
        gAoff[q] = (long)(m0 + row) * K + col;
        int pp = row >> 5, hf = (row >> 4) & 1, wi = row & 15;
        gBoff[q] = (long)(hf * 4096 + n0 + pp * 16 + wi) * K + col;
    }

    #pragma unroll
    for (int q = 0; q < 4; ++q) { STG_A(q, 0, 0); STG_B(q, 0, 0); }
    #pragma unroll
    for (int q = 0; q < 4; ++q) { STG_A(q, 1, 64); STG_B(q, 1, 64); }

    f32x4 acc[8][4] = {};
    const int swz = (cl & 7) << 4;
    const int aRow = (wr * 128 + cl) * 128;
    const int bRow = (wc * 64 + cl) * 128;
    const int cs0 = (qd * 16) ^ swz;
    const int cs1 = (qd * 16 + 64) ^ swz;

    asm volatile("s_waitcnt vmcnt(8)" ::: "memory");
    __builtin_amdgcn_s_barrier();

    GEMM256_LOOP

    #pragma unroll
    for (int m = 0; m < 8; ++m) {
        #pragma unroll
        for (int pr = 0; pr < 2; ++pr) {
            int col = n0 + wc * 32 + pr * 16 + cl;
            float bs1 = bias[col];
            float bs2 = bias[4096 + col];
            #pragma unroll
            for (int i = 0; i < 4; ++i) {
                int row = m0 + wr * 128 + m * 16 + qd * 4 + i;
                float h1 = acc[m][pr * 2 + 0][i] + bs1;
                float h2 = acc[m][pr * 2 + 1][i] + bs2;
                float sg = 1.f / (1.f + __expf(-h2));
                ACT[(long)row * 4096 + col] = __float2bfloat16(h1 * h2 * sg);
            }
        }
    }
}

// ------- 256x128 / BK=64 split-K=2 engine (out-proj: N=1024, K=4096) ---------
#define MFMA_HQ(MH)                                                                       \
    __builtin_amdgcn_s_setprio(1);                                                        \
    _Pragma("unroll")                                                                     \
    for (int m = 0; m < 4; ++m) {                                                         \
        _Pragma("unroll")                                                                 \
        for (int n = 0; n < 2; ++n) {                                                     \
            acc[(MH)*4+m][n] = __builtin_amdgcn_mfma_f32_16x16x32_bf16(                   \
                aF[m][0], bF[n][0], acc[(MH)*4+m][n], 0, 0, 0);                           \
            acc[(MH)*4+m][n] = __builtin_amdgcn_mfma_f32_16x16x32_bf16(                   \
                aF[m][1], bF[n][1], acc[(MH)*4+m][n], 0, 0, 0);                           \
        }                                                                                 \
    }                                                                                     \
    __builtin_amdgcn_s_setprio(0);

__global__ __launch_bounds__(512) void gemm256x128_kernel(
    const bf16* __restrict__ A, const bf16* __restrict__ Bt,
    float* __restrict__ P0, float* __restrict__ P1, int N, int K)
{
    __shared__ bf16 sA[2][16384];
    __shared__ bf16 sB[2][8192];
    const int tid = threadIdx.x;
    const int wave = tid >> 6, lane = tid & 63;
    const int wr = wave >> 2, wc = wave & 3;
    const int cl = lane & 15, qd = lane >> 4;

    const int cpx = gridDim.x >> 3;                 // 256 blocks: %8==0 bijective
    int wg = (blockIdx.x & 7) * cpx + (blockIdx.x >> 3);
    const int split = wg >> 7;                      // K-half
    const int w2 = wg & 127;                        // 16 m-tiles x 8 n-tiles
    const int group_id = w2 >> 6;
    const int pid_in = w2 & 63;
    const int m0 = (group_id * 8 + (pid_in & 7)) * 256;
    const int n0 = (pid_in >> 3) * 128;
    const int Kh = K >> 1;
    A  += (long)split * Kh;
    Bt += (long)split * Kh;

    long gAoff[4], gBoff[2];
    #pragma unroll
    for (int q = 0; q < 4; ++q) {
        int c = tid + q * 512;
        int cs = c ^ ((c >> 3) & 7);
        int row = cs >> 3, col = (cs & 7) * 8;
        gAoff[q] = (long)(m0 + row) * K + col;
        if (q < 2) gBoff[q] = (long)(n0 + row) * K + col;
    }

    const int nt = Kh >> 6;
    // prologue: X+B(0), Y(0), X+B(1)
    STG_A(0, 0, 0); STG_A(2, 0, 0); STG_B(0, 0, 0); STG_B(1, 0, 0);
    STG_A(1, 0, 0); STG_A(3, 0, 0);
    if (nt > 1) { STG_A(0, 1, 64); STG_A(2, 1, 64); STG_B(0, 1, 64); STG_B(1, 1, 64); }

    f32x4 acc[8][2] = {};
    const int swz = (cl & 7) << 4;
    const int aRow = (wr * 128 + cl) * 128;
    const int bRow = (wc * 32 + cl) * 128;
    const int cs0 = (qd * 16) ^ swz;
    const int cs1 = (qd * 16 + 64) ^ swz;

    if (nt > 1) { asm volatile("s_waitcnt vmcnt(4)" ::: "memory"); }
    else        { asm volatile("s_waitcnt vmcnt(0)" ::: "memory"); }
    __builtin_amdgcn_s_barrier();

    for (int t = 0; t < nt; ++t) {
        const int pb = t & 1;
        const char* cA = (const char*)sA[pb];
        const char* cB = (const char*)sB[pb];
        bf16x8 aF[4][2], bF[2][2];
        // P1: read A-mh0 (8) + B (4); stage Y(t+1) -> buf[pb^1]
        #pragma unroll
        for (int m = 0; m < 4; ++m) {
            aF[m][0] = *(const bf16x8*)(cA + aRow + m * 2048 + cs0);
            aF[m][1] = *(const bf16x8*)(cA + aRow + m * 2048 + cs1);
        }
        #pragma unroll
        for (int n = 0; n < 2; ++n) {
            bF[n][0] = *(const bf16x8*)(cB + bRow + n * 2048 + cs0);
            bF[n][1] = *(const bf16x8*)(cB + bRow + n * 2048 + cs1);
        }
        if (t + 1 < nt) { STG_A(1, pb ^ 1, (t + 1) << 6); STG_A(3, pb ^ 1, (t + 1) << 6); }
        __builtin_amdgcn_s_barrier();
        asm volatile("s_waitcnt lgkmcnt(0)" ::: "memory");
        MFMA_HQ(0)
        __builtin_amdgcn_s_barrier();
        // P2: read A-mh1 (8); stage X+B(t+2) -> buf[pb]
        #pragma unroll
        for (int m = 0; m < 4; ++m) {
            aF[m][0] = *(const bf16x8*)(cA + aRow + 8192 + m * 2048 + cs0);
            aF[m][1] = *(const bf16x8*)(cA + aRow + 8192 + m * 2048 + cs1);
        }
        if (t + 2 < nt) { STG_A(0, pb, (t + 2) << 6); STG_A(2, pb, (t + 2) << 6);
                          STG_B(0, pb, (t + 2) << 6); STG_B(1, pb, (t + 2) << 6); }
        __builtin_amdgcn_s_barrier();
        asm volatile("s_waitcnt lgkmcnt(0)" ::: "memory");
        MFMA_HQ(1)
        if (t + 2 < nt)      { asm volatile("s_waitcnt vmcnt(4)" ::: "memory"); }
        else if (t + 1 < nt) { asm volatile("s_waitcnt vmcnt(0)" ::: "memory"); }
        __builtin_amdgcn_s_barrier();
    }

    float* P = split ? P1 : P0;
    #pragma unroll
    for (int m = 0; m < 8; ++m) {
        #pragma unroll
        for (int n = 0; n < 2; ++n) {
            int col = n0 + wc * 32 + n * 16 + cl;
            #pragma unroll
            for (int i = 0; i < 4; ++i) {
                int row = m0 + wr * 128 + m * 16 + qd * 4 + i;
                P[(long)row * N + col] = acc[m][n][i];
            }
        }
    }
}

// ------- fuse: out = X1 + gate_mlp * (p0 + p1 + bias)  (float4) --------------
__global__ __launch_bounds__(256) void fuseout_kernel(
    const float* __restrict__ p0, const float* __restrict__ p1,
    const float* __restrict__ bias, const float* __restrict__ resid,
    const float* __restrict__ gates, float* __restrict__ out)
{
    int idx = blockIdx.x * 256 + threadIdx.x;     // over 4096*1024/4
    int row = idx >> 8;
    int b = row >> 10;
    int c4 = (idx & 255) * 4;
    float4 a = ((const float4*)p0)[idx];
    float4 c = ((const float4*)p1)[idx];
    float4 r = ((const float4*)resid)[idx];
    float4 bb = *(const float4*)&bias[c4];
    float4 gg = *(const float4*)&gates[b * 2048 + 1024 + c4];
    float4 o;
    o.x = r.x + gg.x * (a.x + c.x + bb.x);
    o.y = r.y + gg.y * (a.y + c.y + bb.y);
    o.z = r.z + gg.z * (a.z + c.z + bb.z);
    o.w = r.w + gg.w * (a.w + c.w + bb.w);
    ((float4*)out)[idx] = o;
}

// ---------------- 64x64-tile bf16 MFMA GEMM (proj; R5-proven best) -----------
__global__ __launch_bounds__(256) void gemm64_kernel(
    const bf16* __restrict__ A, const bf16* __restrict__ Bt,
    const float* __restrict__ bias,
    bf16* __restrict__ Cb, float* __restrict__ Cf,
    const float* __restrict__ resid, const float* __restrict__ gates, int gate_off,
    int Mrows, int N, int K, int mode)
{
    __shared__ bf16 sA[64 * 32];
    __shared__ bf16 sB[64 * 32];
    const int tid = threadIdx.x;
    const int wave = tid >> 6, lane = tid & 63;
    const int num_pid_n = N >> 6;
    const int pid = blockIdx.x;
    const int group_size = 8 * num_pid_n;
    const int group_id = pid / group_size;
    const int pid_in = pid - group_id * group_size;
    const int pid_m = group_id * 8 + (pid_in & 7);
    const int pid_n = pid_in >> 3;
    const int m0 = pid_m * 64, n0 = pid_n * 64;
    const int wm = (wave & 1) * 32, wn = (wave >> 1) * 32;
    const int cl = lane & 15, qd = lane >> 4;

    f32x4 acc[2][2] = {};

    const int c = tid;
    const int rr = c >> 2, ss = (c & 3) ^ ((c >> 3) & 3);
    const bf16* gA = A + (long)(m0 + rr) * K + ss * 8;
    const bf16* gB = Bt + (long)(n0 + rr) * K + ss * 8;
    bf16* lA = &sA[wave * 512];
    bf16* lB = &sB[wave * 512];

    const int q8s = (qd ^ ((cl >> 1) & 3)) * 8;

    for (int kc = 0; kc < K; kc += 32) {
        gl_lds16(gA + kc, lA);
        gl_lds16(gB + kc, lB);
        __syncthreads();
        bf16x8 af[2], bfr[2];
        #pragma unroll
        for (int t = 0; t < 2; ++t)
            af[t] = *(const bf16x8*)&sA[(wm + cl + t * 16) * 32 + q8s];
        #pragma unroll
        for (int u = 0; u < 2; ++u)
            bfr[u] = *(const bf16x8*)&sB[(wn + cl + u * 16) * 32 + q8s];
        #pragma unroll
        for (int t = 0; t < 2; ++t)
            #pragma unroll
            for (int u = 0; u < 2; ++u)
                acc[t][u] = __builtin_amdgcn_mfma_f32_16x16x32_bf16(af[t], bfr[u], acc[t][u], 0, 0, 0);
        __syncthreads();
    }

    #pragma unroll
    for (int t = 0; t < 2; ++t) {
        #pragma unroll
        for (int u = 0; u < 2; ++u) {
            int col = n0 + wn + u * 16 + cl;
            float bs = bias[col];
            #pragma unroll
            for (int i = 0; i < 4; ++i) {
                int row = m0 + wm + t * 16 + qd * 4 + i;
                float v = acc[t][u][i] + bs;
                if (mode == 0) {
                    Cb[(long)row * N + col] = __float2bfloat16(v);
                } else {
                    int b = row >> 10;
                    float g = gates[b * 2048 + gate_off + col];
                    Cf[(long)row * N + col] = resid[(long)row * N + col] + g * v;
                }
            }
        }
    }
}

// ---------------- fused flash-style attention, fixed-shift softmax ------------
// Q,K rows are RMS-normalized (unit weights) -> scores in [-8,8]; fixed shift 8.
// R14: linear [64][128B] LDS tiles + XOR swizzle, gl_lds w/ pre-swizzled src.
// R15: double-buffered K/V + counted vmcnt(4). R16: Q in registers, 40KB LDS
// (4 blocks/CU), setprio around MFMA clusters.
__global__ __launch_bounds__(256) void attn_kernel(
    const bf16* __restrict__ qh, const bf16* __restrict__ kh, const bf16* __restrict__ vt,
    bf16* __restrict__ ao)
{
    const int bh = blockIdx.y;
    const int q0 = blockIdx.x * 64;
    const int tid = threadIdx.x, wave = tid >> 6, lane = tid & 63;
    const int cl = lane & 15, qd = lane >> 4;

    __shared__ bf16 sK[2][64 * 64];
    __shared__ bf16 sV[2][64 * 64];
    __shared__ bf16 sP[4][16 * 64];

    // staging geometry: thread a -> row = a>>3, source chunk = (a&7)^(row&7)
    const int r0 = tid >> 3;
    const int c0 = (tid & 7) ^ (r0 & 7);
    const int r1 = (tid + 256) >> 3;
    const int c1 = ((tid + 256) & 7) ^ (r1 & 7);

    const bf16* Kg = kh + (long)bh * S_ * 64;
    const bf16* Vg = vt + (long)bh * 64 * S_;

    #define ATTN_STAGE(t) {                                                          \
        int kv = (t) * 64;                                                           \
        gl_lds16(Kg + (long)(kv + r0) * 64 + c0 * 8, &sK[(t) & 1][(long)tid * 8]);   \
        gl_lds16(Kg + (long)(kv + r1) * 64 + c1 * 8, &sK[(t) & 1][(long)(tid + 256) * 8]); \
        gl_lds16(Vg + (long)r0 * S_ + kv + c0 * 8, &sV[(t) & 1][(long)tid * 8]);     \
        gl_lds16(Vg + (long)r1 * S_ + kv + c1 * 8, &sV[(t) & 1][(long)(tid + 256) * 8]); }

    // prologue: Q fragment to registers (issued first), then K/V tile 0
    bf16x8 qf[2];
    {
        const bf16* Qg = qh + (long)bh * S_ * 64 + (long)q0 * 64;
        qf[0] = *(const bf16x8*)&Qg[(wave * 16 + cl) * 64 + qd * 8];
        qf[1] = *(const bf16x8*)&Qg[(wave * 16 + cl) * 64 + 32 + qd * 8];
        ATTN_STAGE(0)
    }

    float l_i[4] = {0.f, 0.f, 0.f, 0.f};
    f32x4 o_acc[4] = {};

    const int swz = (cl & 7) << 4;               // lane-constant read XOR
    char* cP = (char*)sP[wave];

    for (int t = 0; t < 16; ++t) {
        __builtin_amdgcn_s_barrier();            // all waves done reading buf[(t+1)&1]
        if (t + 1 < 16) {
            ATTN_STAGE(t + 1)                    // 4 loads in flight across compute(t)
            asm volatile("s_waitcnt vmcnt(4)" ::: "memory");   // tile t (and qf) landed
        } else {
            asm volatile("s_waitcnt vmcnt(0)" ::: "memory");
        }
        __builtin_amdgcn_s_barrier();            // tile t visible to all waves
        const char* cK = (const char*)sK[t & 1];
        const char* cV = (const char*)sV[t & 1];

        // S = Q_wave (16 x 64) @ K_tile^T  -> 4 col-tiles of 16
        f32x4 sfr[4] = {};
        __builtin_amdgcn_s_setprio(1);
        #pragma unroll
        for (int ks = 0; ks < 2; ++ks) {
            const int co = (ks * 64 + qd * 16) ^ swz;
            #pragma unroll
            for (int u = 0; u < 4; ++u) {
                bf16x8 bk = *(const bf16x8*)(cK + (u * 16 + cl) * 128 + co);
                sfr[u] = __builtin_amdgcn_mfma_f32_16x16x32_bf16(qf[ks], bk, sfr[u], 0, 0, 0);
            }
        }
        __builtin_amdgcn_s_setprio(0);

        // fixed-shift softmax: p = exp(s*0.125 - 8), accumulate l_i
        #pragma unroll
        for (int i = 0; i < 4; ++i) {
            int rowp = qd * 4 + i;
            char* pb = cP + rowp * 128;
            const int xorv = (rowp & 7) << 4;
            float sum = 0.f;
            #pragma unroll
            for (int u = 0; u < 4; ++u) {
                float p = __expf(sfr[u][i] * 0.125f - 8.f);
                sum += p;
                *(bf16*)(pb + ((u * 32 + cl * 2) ^ xorv)) = __float2bfloat16(p);
            }
            sum += __shfl_xor(sum, 1);
            sum += __shfl_xor(sum, 2);
            sum += __shfl_xor(sum, 4);
            sum += __shfl_xor(sum, 8);
            l_i[i] += sum;
        }

        // O += P (16 x 64kv) @ V (64kv x 64d); P read back in A-layout from LDS
        __builtin_amdgcn_s_setprio(1);
        #pragma unroll
        for (int ks = 0; ks < 2; ++ks) {
            const int co = (ks * 64 + qd * 16) ^ swz;
            bf16x8 ap = *(const bf16x8*)(cP + cl * 128 + co);
            #pragma unroll
            for (int u = 0; u < 4; ++u) {
                bf16x8 bv = *(const bf16x8*)(cV + (u * 16 + cl) * 128 + co);
                o_acc[u] = __builtin_amdgcn_mfma_f32_16x16x32_bf16(ap, bv, o_acc[u], 0, 0, 0);
            }
        }
        __builtin_amdgcn_s_setprio(0);
    }
    #undef ATTN_STAGE

    // epilogue: ao[b, s, h*64+d]
    #pragma unroll
    for (int i = 0; i < 4; ++i) {
        float invl = 1.f / l_i[i];
        int row = q0 + wave * 16 + qd * 4 + i;
        #pragma unroll
        for (int u = 0; u < 4; ++u) {
            int d = u * 16 + cl;
            ao[((long)(bh >> 4) * S_ + row) * D_ + (bh & 15) * 64 + d] =
                __float2bfloat16(o_acc[u][i] * invl);
        }
    }
}

extern "C" void kernel_launch(void* const* d_in, const int* in_sizes, int n_in,
                              void* d_out, int out_size, void* d_ws, size_t ws_size,
                              hipStream_t stream) {
    const float* x       = (const float*)d_in[0];
    const float* emb     = (const float*)d_in[1];
    const float* ln1_w   = (const float*)d_in[2];
    const float* ln1_lW  = (const float*)d_in[3];
    const float* ln1_lb  = (const float*)d_in[4];
    const float* ln2_w   = (const float*)d_in[5];
    const float* ln2_lW  = (const float*)d_in[6];
    const float* ln2_lb  = (const float*)d_in[7];
    const float* qkv_W   = (const float*)d_in[8];
    const float* qkv_b   = (const float*)d_in[9];
    const float* proj_W  = (const float*)d_in[10];
    const float* proj_b  = (const float*)d_in[11];
    const float* nq_w    = (const float*)d_in[12];
    const float* nk_w    = (const float*)d_in[13];
    const float* mlp_W   = (const float*)d_in[14];
    const float* mlp_b   = (const float*)d_in[15];
    const float* out_W   = (const float*)d_in[16];
    const float* out_b   = (const float*)d_in[17];
    const float* gates_W = (const float*)d_in[18];
    const float* gates_b = (const float*)d_in[19];
    float* out = (float*)d_out;

    // workspace layout (all offsets 256B aligned)
    char* p = (char*)d_ws;
    if (ws_size < 159481856UL) return;  // loud failure rather than OOB corruption
    bf16* WT_QKV  = (bf16*)p;  p += 6291456;   // [3072][1024]
    bf16* WT_PROJ = (bf16*)p;  p += 2097152;   // [1024][1024]
    bf16* WT_MLP  = (bf16*)p;  p += 16777216;  // [8192][1024]
    bf16* WT_OUT  = (bf16*)p;  p += 8388608;   // [1024][4096]
    float* G      = (float*)p; p += 32768;     // [4][2048]
    float* SSb    = (float*)p; p += 32768;
    float* SS2b   = (float*)p; p += 32768;
    float* X1     = (float*)p; p += 16777216;  // f32 [4096][1024]
    bf16* XN2     = (bf16*)p;  p += 8388608;
    bf16* ACT     = (bf16*)p;  p += 33554432;  // [4096][4096]
    char* REG = p;                              // reused region
    bf16* XN   = (bf16*)(REG);
    bf16* QH   = (bf16*)(REG + 33554432);      // [B,H,S,HD]
    bf16* KH   = (bf16*)(REG + 41943040);
    bf16* VT   = (bf16*)(REG + 50331648);      // [B,H,HD,S]
    bf16* AO   = (bf16*)(REG + 58720256);      // [4096][1024]
    // split-K partials for the out-proj: reuse REG head (XN dead by then)
    float* PF0 = (float*)(REG);                // [4096][1024] f32
    float* PF1 = (float*)(REG + 16777216);
    // rope table: head of X1 (X1 is written only later by the proj GEMM)
    float4* ROPETAB = (float4*)X1;             // [1024][16] float4 = 256 KB

    dim3 blk(256);
    // zero G/SSb/SS2b (96 KB) for embgemm's atomicAdd k-split
    hipMemsetAsync(G, 0, 98304, stream);
    // merged prep: ropetab (64) + 64x64 transposes (4096) + embgemm (96)
    prep_kernel<<<dim3(4256), blk, 0, stream>>>(ROPETAB,
                                                qkv_W, WT_QKV, proj_W, WT_PROJ,
                                                mlp_W, WT_MLP, out_W, WT_OUT,
                                                emb, gates_W, gates_b, ln1_lW, ln1_lb,
                                                ln2_lW, ln2_lb, G, SSb, SS2b);
    rmsmod_kernel<<<dim3(4096), blk, 0, stream>>>(x, ln1_w, SSb, XN);
    // QKV GEMM + fused bias/rope/head-norm/layout: M=4096 N=3072 K=1024
    qkvgemm_kernel<<<dim3(192), dim3(512), 0, stream>>>(XN, WT_QKV, qkv_b, nq_w, nk_w,
                                                        ROPETAB, QH, KH, VT, 3072, 1024);
    attn_kernel<<<dim3(16, 64), blk, 0, stream>>>(QH, KH, VT, AO);
    gemm64_kernel<<<dim3(1024), blk, 0, stream>>>(AO, WT_PROJ, proj_b, nullptr, X1,
                                                  x, G, 0, 4096, 1024, 1024, 1);
    rmsmod_kernel<<<dim3(4096), blk, 0, stream>>>(X1, ln2_w, SS2b, XN2);
    // fused MLP: 16 m-tiles x 32 fused col-tiles = 512 blocks
    gemm256_mlp_kernel<<<dim3(512), dim3(512), 0, stream>>>(XN2, WT_MLP, mlp_b, ACT, 1024);
    // out-proj: 256x128 split-K=2 engine (256 blocks = exact CU fill) + fuse
    gemm256x128_kernel<<<dim3(256), dim3(512), 0, stream>>>(ACT, WT_OUT, PF0, PF1, 1024, 4096);
    fuseout_kernel<<<dim3(4096), blk, 0, stream>>>(PF0, PF1, out_b, X1, G, out);
}